// Round 16
// baseline (7460.839 us; speedup 1.0000x reference)
//
#include <hip/hip_runtime.h>
#include <hip/hip_fp16.h>

typedef unsigned short u16;
typedef unsigned int u32;
typedef unsigned long long u64;

#define NT 512      // time steps
#define NB 256      // batch
#define NH 1024     // hidden
#define NE 128      // emb dim
#define NHE 1152    // H+E
#define NL 17       // labels
#define MT 8        // batch groups (32 rows each)
#define JTILES 32   // hidden-col tiles (32 cols each)
#define XKC 36      // K-chunks (32 wide) for x part
#define HKC 32      // K-chunks for h part
#define KCT 68      // XKC + HKC
#define NBLK 256    // MT * JTILES
#define THREADS 512 // 8 waves, k-split across gates

typedef __attribute__((ext_vector_type(8))) _Float16 half8;
typedef __attribute__((ext_vector_type(4))) float f32x4;

// ---- workspace layout (bytes) ----
#define WS_CNT     0ull
#define WS_HBUF    4096ull
#define WS_WPACK   1052672ull                // 32*68*6*1024     = 13,369,344
#define WS_WOPACK  14422016ull               // 32*2*1024        = 65,536
#define WS_XPACK   14487552ull               // 8*512*36*2*64*16 = 301,989,888
#define WS_TOTAL   316477440ull

#define HB_U64_PER (HKC * 2 * 64 * 2)        // 8192 u64 per (par,m)
#define XSLOT_U16  (XKC * 2 * 64 * 8)        // 36864 u16 per (m,t) x slot (73728B)

__device__ __forceinline__ u16 f2h(float f) {
  __half h = __float2half(f);
  return __builtin_bit_cast(u16, h);
}
__device__ __forceinline__ float h2f(u16 u) {
  return __half2float(__builtin_bit_cast(__half, u));
}
__device__ __forceinline__ uint4 pack8h(const u16* o) {
  uint4 v;
  v.x = (u32)o[0] | ((u32)o[1] << 16);
  v.y = (u32)o[2] | ((u32)o[3] << 16);
  v.z = (u32)o[4] | ((u32)o[5] << 16);
  v.w = (u32)o[6] | ((u32)o[7] << 16);
  return v;
}

// global->LDS DMA, 16B/lane. aux=17 (sc0|sc1): coherent LLC read (h handoff).
__device__ __forceinline__ void gll16u(const void* g, void* l) {
  __builtin_amdgcn_global_load_lds((const __attribute__((address_space(1))) u32*)g,
                                   (__attribute__((address_space(3))) u32*)l, 16, 0, 17);
}
// aux=0: normal cached read (x stream; shared via L2/L3).
__device__ __forceinline__ void gll16c(const void* g, void* l) {
  __builtin_amdgcn_global_load_lds((const __attribute__((address_space(1))) u32*)g,
                                   (__attribute__((address_space(3))) u32*)l, 16, 0, 0);
}

// ---------------- zero flags + h parity-0 ----------------
__global__ void zero_ws(uint4* p) {
  int idx = blockIdx.x * 256 + threadIdx.x;
  if (idx < 33024) {
    uint4 z; z.x = 0; z.y = 0; z.z = 0; z.w = 0;
    p[idx] = z;
  }
}

// ---------------- pack weights into B-fragment order ----------------
__global__ void pack_w(const float* __restrict__ Wih, const float* __restrict__ Whh,
                       const float* __restrict__ Wout, u16* __restrict__ wpack,
                       u16* __restrict__ wopack) {
  int idx = blockIdx.x * 256 + threadIdx.x;
  const int WUNITS = JTILES * KCT * 3 * 2 * 64;   // 835584
  if (idx < WUNITS) {
    int l = idx & 63;
    int r = idx >> 6;
    int ni = r & 1; r >>= 1;
    int g = r % 3;  r /= 3;
    int kc = r % KCT; r /= KCT;
    int jt = r;
    int row = g * NH + jt * 32 + ni * 16 + (l & 15);
    int kk = (l >> 4) * 8;
    const float* src = (kc < XKC) ? (Wih + (size_t)row * NHE + kc * 32 + kk)
                                  : (Whh + (size_t)row * NH + (kc - XKC) * 32 + kk);
    u16 o[8];
#pragma unroll
    for (int e = 0; e < 8; ++e) o[e] = f2h(src[e]);
    ((uint4*)wpack)[idx] = pack8h(o);
  } else if (idx < WUNITS + HKC * 2 * 64) {
    int j = idx - WUNITS;
    int l = j & 63; j >>= 6;
    int ni = j & 1; int kc = j >> 1;
    int col = (l & 15) + 16 * ni;
    int kk = kc * 32 + (l >> 4) * 8;
    u16 o[8];
#pragma unroll
    for (int e = 0; e < 8; ++e)
      o[e] = (col < NL) ? f2h(Wout[(size_t)col * NH + kk + e]) : (u16)0;
    ((uint4*)wopack)[idx - WUNITS] = pack8h(o);
  }
}

// ---------------- pack x = [seg | emb(prev)] into A-fragment order ----------------
__global__ void pack_x(const float* __restrict__ seg, const int* __restrict__ labels,
                       const float* __restrict__ emb, u16* __restrict__ xpack) {
  __shared__ float ls[32][65];
  __shared__ int lbl[32];
  const int bid = blockIdx.x;
  const int t = bid & (NT - 1);
  const int m = bid >> 9;                    // 0..7
  const int tid = threadIdx.x;
  u16* outb = xpack + (size_t)(m * NT + t) * XSLOT_U16;
  const int r = tid >> 3, qq = tid & 7;      // 32 rows x 8 col-chunks
  const int l = tid & 63;

  for (int kc2 = 0; kc2 < 16; ++kc2) {       // stage 64 cols of seg at a time
    const float* s = seg + ((size_t)(m * 32 + r) * NT + t) * NH + kc2 * 64 + qq * 8;
    float4 a = ((const float4*)s)[0];
    float4 b2 = ((const float4*)s)[1];
    ls[r][qq * 8 + 0] = a.x;  ls[r][qq * 8 + 1] = a.y;
    ls[r][qq * 8 + 2] = a.z;  ls[r][qq * 8 + 3] = a.w;
    ls[r][qq * 8 + 4] = b2.x; ls[r][qq * 8 + 5] = b2.y;
    ls[r][qq * 8 + 6] = b2.z; ls[r][qq * 8 + 7] = b2.w;
    __syncthreads();
    const int sub2 = tid >> 6;               // 0..3 -> (kc half, sub)
    const int kc = kc2 * 2 + (sub2 >> 1);
    const int sub = sub2 & 1;
    const int row = sub * 16 + (l & 15);
    const int c0 = (sub2 >> 1) * 32 + (l >> 4) * 8;
    u16 o[8];
#pragma unroll
    for (int e = 0; e < 8; ++e) o[e] = f2h(ls[row][c0 + e]);
    ((uint4*)outb)[(kc * 2 + sub) * 64 + l] = pack8h(o);
    __syncthreads();
  }
  if (tid < 32)
    lbl[tid] = (t == 0) ? NL : labels[(size_t)(m * 32 + tid) * NT + (t - 1)];
  __syncthreads();
#pragma unroll
  for (int k = 0; k < 2; ++k) {
    int u = tid + k * 256;                   // 512 units: kc 32..35, sub, l
    int kc = 32 + (u >> 7);
    int sub = (u >> 6) & 1;
    int ll = u & 63;
    int row = sub * 16 + (ll & 15);
    int c = (kc - 32) * 32 + (ll >> 4) * 8;
    const float* s = emb + (size_t)lbl[row] * NE + c;
    float4 a = ((const float4*)s)[0];
    float4 b2 = ((const float4*)s)[1];
    u16 o[8];
    o[0] = f2h(a.x); o[1] = f2h(a.y); o[2] = f2h(a.z); o[3] = f2h(a.w);
    o[4] = f2h(b2.x); o[5] = f2h(b2.y); o[6] = f2h(b2.z); o[7] = f2h(b2.w);
    ((uint4*)outb)[(kc * 2 + sub) * 64 + ll] = pack8h(o);
  }
}

// ---------------- persistent GRU kernel ----------------
#define MFMA16(a, b, c) __builtin_amdgcn_mfma_f32_16x16x32_f16((a), (b), (c), 0, 0, 0)

// all-lane wait: lane l polls flags[l] (64 flags: sub0 -> 0..31, sub1 -> 32..63)
#define WAIT_FLAGS(tgt) do { \
  while (true) { \
    u32 v_ = __hip_atomic_load(fl + l, __ATOMIC_RELAXED, __HIP_MEMORY_SCOPE_AGENT); \
    if (__all((int)v_ >= (tgt))) break; \
  } \
} while (0)

// issue x(tt) DMA into xlds (not drained here): 4608 units / 512 threads = 9
#define ISSUE_X(tt) do { \
  const char* xgb_ = (const char*)xpack + (size_t)(m * NT + (tt)) * (XSLOT_U16 * 2); \
  _Pragma("unroll") \
  for (int k_ = 0; k_ < 9; ++k_) \
    gll16c(xgb_ + ((size_t)(k_ * 512 + tid)) * 16, (void*)(xlds + (k_ * 512 + w * 64))); \
} while (0)

__global__ __launch_bounds__(THREADS, 1)
void gru_persist(u16* xpack, const u16* __restrict__ wpack,
                 const float* __restrict__ bih, const float* __restrict__ bhh,
                 u64* __restrict__ hbuf, u32* __restrict__ counters) {
  __shared__ uint4 hlds[HKC * 2 * 64];           // 64KB h(t) tile (frag-linear)
  __shared__ uint4 xlds[XKC * 2 * 64];           // 72KB x(t) tile (frag-linear)
  __shared__ u32 glds16[8 * 2 * 2 * 2 * 64];     // 16KB fp16 gate partials (8 tasks)
  __shared__ u16 hbf[32 * 40];                   // 2.5KB fp16 bounce

  const int bid = blockIdx.x;
  const int xcd = bid & 7;
  const int q = bid >> 3;
  const int m = q & 7;
  const int jslot = q >> 3;
  const int jt = jslot * 8 + xcd;            // weights L2-resident per XCD
  const int tid = threadIdx.x;
  const int w = tid >> 6, l = tid & 63;
  const int l15 = l & 15, l4 = l >> 4;
  const int usub = (w >> 1) & 1, uni = w & 1; // update subtile for waves 0-3

  const uint4* wp = (const uint4*)wpack;
  u32* fl = counters + m * 128;              // 64 flags per group (512B stride)
  const size_t wbase_u = (size_t)jt * (KCT * 6 * 64);

  const int ocol = jt * 32 + uni * 16 + l15;
  const float br = bih[ocol] + bhh[ocol];
  const float bz = bih[NH + ocol] + bhh[NH + ocol];
  const float bxn = bih[2 * NH + ocol];
  const float bhn = bhh[2 * NH + ocol];
  float hold[4] = {0.f, 0.f, 0.f, 0.f};
  const f32x4 z4 = {0.f, 0.f, 0.f, 0.f};

  // wave task table: w0,w1,w2 -> R(x1,x2,h); w3,w4,w5 -> Z(x1,x2,h);
  // w6 -> XN(x); w7 -> HN(h). max 36 kc per wave.
  int tg, tkc0, tkcn; bool tIsX;
  if (w == 6)      { tg = 2; tIsX = true;  tkc0 = 0;  tkcn = 36; }
  else if (w == 7) { tg = 2; tIsX = false; tkc0 = 0;  tkcn = 32; }
  else {
    tg = (w < 3) ? 0 : 1;
    const int r_ = (w < 3) ? w : (w - 3);
    tIsX = (r_ < 2);
    tkc0 = (r_ == 1) ? 18 : 0;
    tkcn = tIsX ? ((r_ == 0) ? 18 : 36) : 32;
  }
  const int tkadd = tIsX ? 0 : XKC;          // kc -> wpack kc index offset
  const uint4* asrc = tIsX ? xlds : hlds;

  // archive-store thread mapping (2KB chunk jt of hlds -> dead xpack slot)
  const int a_sub = (tid >> 7) & 1, a_half = (tid >> 6) & 1, a_l = tid & 63;
  const size_t a_off = ((size_t)(jt * 2 + a_sub) * 64 + a_l) * 2 + a_half;

  // ---- prologue: issue x(0) ----
  ISSUE_X(0);

  for (int t = 0; t < NT; ++t) {
    const int par = t & 1;

    // ---- wait for group's h(t) (x(t) DMA already in flight) ----
    WAIT_FLAGS(t);

    // ---- DMA h(t) (coherent LLC); drain x+h together ----
    {
      const char* gb = (const char*)hbuf + ((size_t)(par * MT + m) * HB_U64_PER) * 8;
#pragma unroll
      for (int k = 0; k < 8; ++k)
        gll16u(gb + ((size_t)(k * 512 + tid)) * 16, (void*)(hlds + (k * 512 + w * 64)));
      asm volatile("s_waitcnt vmcnt(0)" ::: "memory");
      __syncthreads();                       // B1: hlds + xlds ready
    }

    // ---- archive h(t) chunk jt into dead xpack slot (m, t-1) ----
    if (t > 0 && tid < 256) {
      const u64 v = ((const u64*)hlds)[a_off];
      u64* dst = (u64*)(xpack + (size_t)(m * NT + (t - 1)) * XSLOT_U16);
      dst[a_off] = v;
    }

    // ---- MFMA phase: wave's (gate, k-range) task ----
    f32x4 acc[2][2];
    acc[0][0] = z4; acc[0][1] = z4; acc[1][0] = z4; acc[1][1] = z4;
#pragma unroll 4
    for (int kc = tkc0; kc < tkcn; ++kc) {
      const int kcw = kc + tkadd;
      uint4 A0 = asrc[(kc * 2 + 0) * 64 + l];
      uint4 A1 = asrc[(kc * 2 + 1) * 64 + l];
      uint4 B0 = wp[wbase_u + (size_t)((kcw * 3 + tg) * 2 + 0) * 64 + l];
      uint4 B1 = wp[wbase_u + (size_t)((kcw * 3 + tg) * 2 + 1) * 64 + l];
      half8 a0 = __builtin_bit_cast(half8, A0);
      half8 a1 = __builtin_bit_cast(half8, A1);
      half8 b0 = __builtin_bit_cast(half8, B0);
      half8 b1 = __builtin_bit_cast(half8, B1);
      acc[0][0] = MFMA16(a0, b0, acc[0][0]);
      acc[0][1] = MFMA16(a0, b1, acc[0][1]);
      acc[1][0] = MFMA16(a1, b0, acc[1][0]);
      acc[1][1] = MFMA16(a1, b1, acc[1][1]);
    }

    // ---- publish fp16 partial tiles (task w) ----
#pragma unroll
    for (int s = 0; s < 2; ++s)
#pragma unroll
      for (int n = 0; n < 2; ++n)
#pragma unroll
        for (int rgp = 0; rgp < 2; ++rgp) {
          u32 v = (u32)f2h(acc[s][n][rgp * 2]) |
                  ((u32)f2h(acc[s][n][rgp * 2 + 1]) << 16);
          glds16[((((w * 2 + s) * 2 + n) * 2 + rgp)) * 64 + l] = v;
        }
    __syncthreads();                         // B2: all partials + xlds reads done

    // ---- gate math (waves 0-3 own subtiles) ----
    if (w < 4) {
      float gv[8][4];
#pragma unroll
      for (int task = 0; task < 8; ++task)
#pragma unroll
        for (int rgp = 0; rgp < 2; ++rgp) {
          u32 v = glds16[((((task * 2 + usub) * 2 + uni) * 2 + rgp)) * 64 + l];
          gv[task][rgp * 2]     = h2f((u16)v);
          gv[task][rgp * 2 + 1] = h2f((u16)(v >> 16));
        }
#pragma unroll
      for (int rg = 0; rg < 4; ++rg) {
        float R   = gv[0][rg] + gv[1][rg] + gv[2][rg] + br;
        float Z   = gv[3][rg] + gv[4][rg] + gv[5][rg] + bz;
        float XNv = gv[6][rg] + bxn;
        float HNv = gv[7][rg] + bhn;
        float r_ = 1.f / (1.f + __expf(-R));
        float z_ = 1.f / (1.f + __expf(-Z));
        float pre = XNv + r_ * HNv;
        float e2 = __expf(2.f * pre);
        float n_ = 1.f - 2.f / (e2 + 1.f);
        float hn_ = (1.f - z_) * n_ + z_ * hold[rg];
        hold[rg] = hn_;
        hbf[(usub * 16 + l4 * 4 + rg) * 40 + uni * 16 + l15] = f2h(hn_);
      }
    }
    __syncthreads();                         // B3: hbf ready

    // ---- waves 0,1: store own h unit, drain OWN stores, flag own sub ----
    // (no block barrier: per-wave vmcnt(0) ACKs this wave's stores at the LLC
    //  before its flag issues; consumer requires BOTH sub-flags >= t+1)
    if (w < 2) {
      const int row = w * 16 + l15;
      const uint4 hv = *(const uint4*)&hbf[(size_t)row * 40 + l4 * 8];
      u64 lo = ((u64)hv.y << 32) | (u64)hv.x;
      u64 hi = ((u64)hv.w << 32) | (u64)hv.z;
      u64* dst = hbuf + (size_t)((par ^ 1) * MT + m) * HB_U64_PER
                      + ((size_t)(jt * 2 + w) * 64 + l) * 2;
      __hip_atomic_store(dst, lo, __ATOMIC_RELAXED, __HIP_MEMORY_SCOPE_AGENT);
      __hip_atomic_store(dst + 1, hi, __ATOMIC_RELAXED, __HIP_MEMORY_SCOPE_AGENT);
      asm volatile("s_waitcnt vmcnt(0)" ::: "memory");
      if (l == 0)
        __hip_atomic_store(fl + w * 32 + jt, (u32)(t + 1),
                           __ATOMIC_RELAXED, __HIP_MEMORY_SCOPE_AGENT);
    }

    // ---- prefetch x(t+1): w2-7 issue during w0/w1's store+flag tail ----
    if (t + 1 < NT) ISSUE_X(t + 1);
  }
}

// ---------------- logits pass: out[b, s, :] = hs[s] @ Wout^T + bout ----------------
__global__ __launch_bounds__(256, 1)
void logits_pass(const u16* __restrict__ harch, const u64* __restrict__ hbuf,
                 const u16* __restrict__ wopack, const float* __restrict__ bout,
                 float* __restrict__ out) {
  __shared__ uint4 hlds[HKC * 2 * 64];       // 64KB h tile
  __shared__ f32x4 redv[4 * 3 * 64];         // 3KB exchange
  const int bid = blockIdx.x;
  const int m = bid >> 9;                    // 0..7
  const int s = bid & 511;                   // 0..511
  const int tid = threadIdx.x;
  const int w = tid >> 6, l = tid & 63;
  const int l15 = l & 15, l4 = l >> 4;
  const int usub = w >> 1, uni = w & 1;
  const uint4* wo = (const uint4*)wopack;
  const f32x4 z4 = {0.f, 0.f, 0.f, 0.f};

  // stage h tile: slot s<511 from archive, s==511 from hbuf parity 0
  const char* gb = (s < 511)
      ? (const char*)(harch + (size_t)(m * NT + s) * XSLOT_U16)
      : (const char*)(hbuf + (size_t)(0 * MT + m) * HB_U64_PER);
#pragma unroll
  for (int k = 0; k < 16; ++k)
    gll16c(gb + ((size_t)(k * 256 + tid)) * 16, (void*)(hlds + (k * 256 + w * 64)));
  asm volatile("s_waitcnt vmcnt(0)" ::: "memory");
  __syncthreads();

  f32x4 aL[2][2];
  aL[0][0] = z4; aL[0][1] = z4; aL[1][0] = z4; aL[1][1] = z4;
#pragma unroll
  for (int c_ = 0; c_ < 8; ++c_) {
    const int kc_ = w * 8 + c_;
    uint4 A0 = hlds[(kc_ * 2 + 0) * 64 + l];
    uint4 A1 = hlds[(kc_ * 2 + 1) * 64 + l];
    uint4 O0 = wo[(size_t)(kc_ * 2 + 0) * 64 + l];
    uint4 O1 = wo[(size_t)(kc_ * 2 + 1) * 64 + l];
    half8 a0 = __builtin_bit_cast(half8, A0);
    half8 a1 = __builtin_bit_cast(half8, A1);
    half8 o0 = __builtin_bit_cast(half8, O0);
    half8 o1 = __builtin_bit_cast(half8, O1);
    aL[0][0] = MFMA16(a0, o0, aL[0][0]);
    aL[0][1] = MFMA16(a0, o1, aL[0][1]);
    aL[1][0] = MFMA16(a1, o0, aL[1][0]);
    aL[1][1] = MFMA16(a1, o1, aL[1][1]);
  }
  f32x4 sL;
#pragma unroll
  for (int o = 0; o < 4; ++o) {
    if (o == w) sL = aL[usub][uni];
    else {
      const int slot = (w > o) ? (w - 1) : w;
      redv[(o * 3 + slot) * 64 + l] = aL[o >> 1][o & 1];
    }
  }
  __syncthreads();
#pragma unroll
  for (int slot = 0; slot < 3; ++slot)
    sL += redv[(w * 3 + slot) * 64 + l];
  const int col = uni * 16 + l15;
  if (col < NL) {
#pragma unroll
    for (int rg = 0; rg < 4; ++rg) {
      const int row = usub * 16 + l4 * 4 + rg;
      const size_t b_ = (size_t)m * 32 + row;
      out[(b_ * NT + s) * NL + col] = sL[rg] + bout[col];
    }
  }
}

extern "C" void kernel_launch(void* const* d_in, const int* in_sizes, int n_in,
                              void* d_out, int out_size, void* d_ws, size_t ws_size,
                              hipStream_t stream) {
  (void)in_sizes; (void)n_in; (void)out_size;
  const float* seg   = (const float*)d_in[0];
  const int*   labels= (const int*)d_in[1];
  const float* emb   = (const float*)d_in[2];
  const float* Wih   = (const float*)d_in[3];
  const float* Whh   = (const float*)d_in[4];
  const float* bih   = (const float*)d_in[5];
  const float* bhh   = (const float*)d_in[6];
  const float* Wout  = (const float*)d_in[7];
  const float* bout  = (const float*)d_in[8];
  float* out = (float*)d_out;
  char* ws = (char*)d_ws;
  if (ws_size < WS_TOTAL) return;

  zero_ws<<<129, 256, 0, stream>>>((uint4*)(ws + WS_CNT));
  pack_w<<<3280, 256, 0, stream>>>(Wih, Whh, Wout,
                                   (u16*)(ws + WS_WPACK), (u16*)(ws + WS_WOPACK));
  pack_x<<<4096, 256, 0, stream>>>(seg, labels, emb, (u16*)(ws + WS_XPACK));
  gru_persist<<<NBLK, THREADS, 0, stream>>>(
      (u16*)(ws + WS_XPACK), (const u16*)(ws + WS_WPACK), bih, bhh,
      (u64*)(ws + WS_HBUF), (u32*)(ws + WS_CNT));
  logits_pass<<<MT * NT, 256, 0, stream>>>(
      (const u16*)(ws + WS_XPACK), (const u64*)(ws + WS_HBUF),
      (const u16*)(ws + WS_WOPACK), bout, out);
}

// Round 17
// 4530.099 us; speedup vs baseline: 1.6469x; 1.6469x over previous
//
#include <hip/hip_runtime.h>
#include <hip/hip_fp16.h>

typedef unsigned short u16;
typedef unsigned int u32;
typedef unsigned long long u64;

#define NT 512      // time steps
#define NB 256      // batch
#define NH 1024     // hidden
#define NE 128      // emb dim
#define NHE 1152    // H+E
#define NL 17       // labels
#define MT 8        // batch groups (32 rows each)
#define JTILES 32   // hidden-col tiles (32 cols each)
#define XKC 36      // K-chunks (32 wide) for x part
#define HKC 32      // K-chunks for h part
#define KCT 68      // XKC + HKC
#define NBLK 256    // MT * JTILES
#define THREADS 512 // 8 waves, k-split across gates

typedef __attribute__((ext_vector_type(8))) _Float16 half8;
typedef __attribute__((ext_vector_type(4))) float f32x4;

// ---- workspace layout (bytes) ----
#define WS_CNT     0ull
#define WS_HBUF    4096ull
#define WS_WPACK   1052672ull                // 32*68*6*1024     = 13,369,344
#define WS_WOPACK  14422016ull               // 32*2*1024        = 65,536
#define WS_XPACK   14487552ull               // 8*512*36*2*64*16 = 301,989,888
#define WS_TOTAL   316477440ull

#define HB_U64_PER (HKC * 2 * 64 * 2)        // 8192 u64 per (par,m)
#define XSLOT_U16  (XKC * 2 * 64 * 8)        // 36864 u16 per (m,t) x slot (73728B)

__device__ __forceinline__ u16 f2h(float f) {
  __half h = __float2half(f);
  return __builtin_bit_cast(u16, h);
}
__device__ __forceinline__ float h2f(u16 u) {
  return __half2float(__builtin_bit_cast(__half, u));
}
__device__ __forceinline__ uint4 pack8h(const u16* o) {
  uint4 v;
  v.x = (u32)o[0] | ((u32)o[1] << 16);
  v.y = (u32)o[2] | ((u32)o[3] << 16);
  v.z = (u32)o[4] | ((u32)o[5] << 16);
  v.w = (u32)o[6] | ((u32)o[7] << 16);
  return v;
}

// global->LDS DMA, 16B/lane. aux=17 (sc0|sc1): coherent LLC read (h handoff).
__device__ __forceinline__ void gll16u(const void* g, void* l) {
  __builtin_amdgcn_global_load_lds((const __attribute__((address_space(1))) u32*)g,
                                   (__attribute__((address_space(3))) u32*)l, 16, 0, 17);
}
// aux=0: normal cached read (x stream; shared via L2/L3).
__device__ __forceinline__ void gll16c(const void* g, void* l) {
  __builtin_amdgcn_global_load_lds((const __attribute__((address_space(1))) u32*)g,
                                   (__attribute__((address_space(3))) u32*)l, 16, 0, 0);
}

// ---------------- zero flags + h parity-0 ----------------
__global__ void zero_ws(uint4* p) {
  int idx = blockIdx.x * 256 + threadIdx.x;
  if (idx < 33024) {
    uint4 z; z.x = 0; z.y = 0; z.z = 0; z.w = 0;
    p[idx] = z;
  }
}

// ---------------- pack weights into B-fragment order ----------------
__global__ void pack_w(const float* __restrict__ Wih, const float* __restrict__ Whh,
                       const float* __restrict__ Wout, u16* __restrict__ wpack,
                       u16* __restrict__ wopack) {
  int idx = blockIdx.x * 256 + threadIdx.x;
  const int WUNITS = JTILES * KCT * 3 * 2 * 64;   // 835584
  if (idx < WUNITS) {
    int l = idx & 63;
    int r = idx >> 6;
    int ni = r & 1; r >>= 1;
    int g = r % 3;  r /= 3;
    int kc = r % KCT; r /= KCT;
    int jt = r;
    int row = g * NH + jt * 32 + ni * 16 + (l & 15);
    int kk = (l >> 4) * 8;
    const float* src = (kc < XKC) ? (Wih + (size_t)row * NHE + kc * 32 + kk)
                                  : (Whh + (size_t)row * NH + (kc - XKC) * 32 + kk);
    u16 o[8];
#pragma unroll
    for (int e = 0; e < 8; ++e) o[e] = f2h(src[e]);
    ((uint4*)wpack)[idx] = pack8h(o);
  } else if (idx < WUNITS + HKC * 2 * 64) {
    int j = idx - WUNITS;
    int l = j & 63; j >>= 6;
    int ni = j & 1; int kc = j >> 1;
    int col = (l & 15) + 16 * ni;
    int kk = kc * 32 + (l >> 4) * 8;
    u16 o[8];
#pragma unroll
    for (int e = 0; e < 8; ++e)
      o[e] = (col < NL) ? f2h(Wout[(size_t)col * NH + kk + e]) : (u16)0;
    ((uint4*)wopack)[idx - WUNITS] = pack8h(o);
  }
}

// ---------------- pack x = [seg | emb(prev)] into A-fragment order ----------------
__global__ void pack_x(const float* __restrict__ seg, const int* __restrict__ labels,
                       const float* __restrict__ emb, u16* __restrict__ xpack) {
  __shared__ float ls[32][65];
  __shared__ int lbl[32];
  const int bid = blockIdx.x;
  const int t = bid & (NT - 1);
  const int m = bid >> 9;                    // 0..7
  const int tid = threadIdx.x;
  u16* outb = xpack + (size_t)(m * NT + t) * XSLOT_U16;
  const int r = tid >> 3, qq = tid & 7;      // 32 rows x 8 col-chunks
  const int l = tid & 63;

  for (int kc2 = 0; kc2 < 16; ++kc2) {       // stage 64 cols of seg at a time
    const float* s = seg + ((size_t)(m * 32 + r) * NT + t) * NH + kc2 * 64 + qq * 8;
    float4 a = ((const float4*)s)[0];
    float4 b2 = ((const float4*)s)[1];
    ls[r][qq * 8 + 0] = a.x;  ls[r][qq * 8 + 1] = a.y;
    ls[r][qq * 8 + 2] = a.z;  ls[r][qq * 8 + 3] = a.w;
    ls[r][qq * 8 + 4] = b2.x; ls[r][qq * 8 + 5] = b2.y;
    ls[r][qq * 8 + 6] = b2.z; ls[r][qq * 8 + 7] = b2.w;
    __syncthreads();
    const int sub2 = tid >> 6;               // 0..3 -> (kc half, sub)
    const int kc = kc2 * 2 + (sub2 >> 1);
    const int sub = sub2 & 1;
    const int row = sub * 16 + (l & 15);
    const int c0 = (sub2 >> 1) * 32 + (l >> 4) * 8;
    u16 o[8];
#pragma unroll
    for (int e = 0; e < 8; ++e) o[e] = f2h(ls[row][c0 + e]);
    ((uint4*)outb)[(kc * 2 + sub) * 64 + l] = pack8h(o);
    __syncthreads();
  }
  if (tid < 32)
    lbl[tid] = (t == 0) ? NL : labels[(size_t)(m * 32 + tid) * NT + (t - 1)];
  __syncthreads();
#pragma unroll
  for (int k = 0; k < 2; ++k) {
    int u = tid + k * 256;                   // 512 units: kc 32..35, sub, l
    int kc = 32 + (u >> 7);
    int sub = (u >> 6) & 1;
    int ll = u & 63;
    int row = sub * 16 + (ll & 15);
    int c = (kc - 32) * 32 + (ll >> 4) * 8;
    const float* s = emb + (size_t)lbl[row] * NE + c;
    float4 a = ((const float4*)s)[0];
    float4 b2 = ((const float4*)s)[1];
    u16 o[8];
    o[0] = f2h(a.x); o[1] = f2h(a.y); o[2] = f2h(a.z); o[3] = f2h(a.w);
    o[4] = f2h(b2.x); o[5] = f2h(b2.y); o[6] = f2h(b2.z); o[7] = f2h(b2.w);
    ((uint4*)outb)[(kc * 2 + sub) * 64 + ll] = pack8h(o);
  }
}

// ---------------- persistent GRU kernel ----------------
#define MFMA16(a, b, c) __builtin_amdgcn_mfma_f32_16x16x32_f16((a), (b), (c), 0, 0, 0)

// all-lane wait: lane l polls flags[l&31] until all >= tgt
#define WAIT_FLAGS(tgt) do { \
  while (true) { \
    u32 v_ = __hip_atomic_load(fl + (l & 31), __ATOMIC_RELAXED, __HIP_MEMORY_SCOPE_AGENT); \
    if (__all((int)v_ >= (tgt))) break; \
  } \
} while (0)

// issue x(tt) DMA into xlds (not drained here): 4608 units / 512 threads = 9
#define ISSUE_X(tt) do { \
  const char* xgb_ = (const char*)xpack + (size_t)(m * NT + (tt)) * (XSLOT_U16 * 2); \
  _Pragma("unroll") \
  for (int k_ = 0; k_ < 9; ++k_) \
    gll16c(xgb_ + ((size_t)(k_ * 512 + tid)) * 16, (void*)(xlds + (k_ * 512 + w * 64))); \
} while (0)

__global__ __launch_bounds__(THREADS, 1)
void gru_persist(u16* xpack, const u16* __restrict__ wpack,
                 const float* __restrict__ bih, const float* __restrict__ bhh,
                 u64* __restrict__ hbuf, u32* __restrict__ counters) {
  __shared__ uint4 hlds[HKC * 2 * 64];           // 64KB h(t) tile (frag-linear)
  __shared__ uint4 xlds[XKC * 2 * 64];           // 72KB x(t) tile (frag-linear)
  __shared__ u32 glds16[8 * 2 * 2 * 2 * 64];     // 16KB fp16 gate partials (8 tasks)
  __shared__ u16 hbf[32 * 40];                   // 2.5KB fp16 bounce

  const int bid = blockIdx.x;
  const int xcd = bid & 7;
  const int q = bid >> 3;
  const int m = q & 7;
  const int jslot = q >> 3;
  const int jt = jslot * 8 + xcd;            // weights L2-resident per XCD
  const int tid = threadIdx.x;
  const int w = tid >> 6, l = tid & 63;
  const int l15 = l & 15, l4 = l >> 4;
  const int usub = (w >> 1) & 1, uni = w & 1; // update subtile for waves 0-3

  const uint4* wp = (const uint4*)wpack;
  u32* fl = counters + m * 64;               // 32 flags per group
  const size_t wbase_u = (size_t)jt * (KCT * 6 * 64);

  const int ocol = jt * 32 + uni * 16 + l15;
  const float br = bih[ocol] + bhh[ocol];
  const float bz = bih[NH + ocol] + bhh[NH + ocol];
  const float bxn = bih[2 * NH + ocol];
  const float bhn = bhh[2 * NH + ocol];
  float hold[4] = {0.f, 0.f, 0.f, 0.f};
  const f32x4 z4 = {0.f, 0.f, 0.f, 0.f};

  // wave task table: w0,w1,w2 -> R(x1,x2,h); w3,w4,w5 -> Z(x1,x2,h);
  // w6 -> XN(x); w7 -> HN(h). max 36 kc per wave.
  int tg, tkc0, tkcn; bool tIsX;
  if (w == 6)      { tg = 2; tIsX = true;  tkc0 = 0;  tkcn = 36; }
  else if (w == 7) { tg = 2; tIsX = false; tkc0 = 0;  tkcn = 32; }
  else {
    tg = (w < 3) ? 0 : 1;
    const int r_ = (w < 3) ? w : (w - 3);
    tIsX = (r_ < 2);
    tkc0 = (r_ == 1) ? 18 : 0;
    tkcn = tIsX ? ((r_ == 0) ? 18 : 36) : 32;
  }
  const int tkadd = tIsX ? 0 : XKC;          // kc -> wpack kc index offset
  const uint4* asrc = tIsX ? xlds : hlds;

  // archive-store thread mapping (2KB chunk jt of hlds -> dead xpack slot)
  const int a_sub = (tid >> 7) & 1, a_half = (tid >> 6) & 1, a_l = tid & 63;
  const size_t a_off = ((size_t)(jt * 2 + a_sub) * 64 + a_l) * 2 + a_half;

  // ---- prologue: issue x(0) ----
  ISSUE_X(0);

  for (int t = 0; t < NT; ++t) {
    const int par = t & 1;

    // ---- wait for group's h(t) (x(t) DMA already in flight) ----
    WAIT_FLAGS(t);

    // ---- DMA h(t) (coherent LLC); drain x+h together ----
    {
      const char* gb = (const char*)hbuf + ((size_t)(par * MT + m) * HB_U64_PER) * 8;
#pragma unroll
      for (int k = 0; k < 8; ++k)
        gll16u(gb + ((size_t)(k * 512 + tid)) * 16, (void*)(hlds + (k * 512 + w * 64)));
      asm volatile("s_waitcnt vmcnt(0)" ::: "memory");
      __syncthreads();                       // B1: hlds + xlds ready
    }

    // ---- archive h(t) chunk jt into dead xpack slot (m, t-1) ----
    if (t > 0 && tid < 256) {
      const u64 v = ((const u64*)hlds)[a_off];
      u64* dst = (u64*)(xpack + (size_t)(m * NT + (t - 1)) * XSLOT_U16);
      dst[a_off] = v;
    }

    // ---- MFMA phase: wave's (gate, k-range) task ----
    f32x4 acc[2][2];
    acc[0][0] = z4; acc[0][1] = z4; acc[1][0] = z4; acc[1][1] = z4;
#pragma unroll 4
    for (int kc = tkc0; kc < tkcn; ++kc) {
      const int kcw = kc + tkadd;
      uint4 A0 = asrc[(kc * 2 + 0) * 64 + l];
      uint4 A1 = asrc[(kc * 2 + 1) * 64 + l];
      uint4 B0 = wp[wbase_u + (size_t)((kcw * 3 + tg) * 2 + 0) * 64 + l];
      uint4 B1 = wp[wbase_u + (size_t)((kcw * 3 + tg) * 2 + 1) * 64 + l];
      half8 a0 = __builtin_bit_cast(half8, A0);
      half8 a1 = __builtin_bit_cast(half8, A1);
      half8 b0 = __builtin_bit_cast(half8, B0);
      half8 b1 = __builtin_bit_cast(half8, B1);
      acc[0][0] = MFMA16(a0, b0, acc[0][0]);
      acc[0][1] = MFMA16(a0, b1, acc[0][1]);
      acc[1][0] = MFMA16(a1, b0, acc[1][0]);
      acc[1][1] = MFMA16(a1, b1, acc[1][1]);
    }

    // ---- publish fp16 partial tiles (task w) ----
#pragma unroll
    for (int s = 0; s < 2; ++s)
#pragma unroll
      for (int n = 0; n < 2; ++n)
#pragma unroll
        for (int rgp = 0; rgp < 2; ++rgp) {
          u32 v = (u32)f2h(acc[s][n][rgp * 2]) |
                  ((u32)f2h(acc[s][n][rgp * 2 + 1]) << 16);
          glds16[((((w * 2 + s) * 2 + n) * 2 + rgp)) * 64 + l] = v;
        }
    __syncthreads();                         // B2: all partials + xlds reads done

    // ---- gate math (waves 0-3 own subtiles) ----
    if (w < 4) {
      float gv[8][4];
#pragma unroll
      for (int task = 0; task < 8; ++task)
#pragma unroll
        for (int rgp = 0; rgp < 2; ++rgp) {
          u32 v = glds16[((((task * 2 + usub) * 2 + uni) * 2 + rgp)) * 64 + l];
          gv[task][rgp * 2]     = h2f((u16)v);
          gv[task][rgp * 2 + 1] = h2f((u16)(v >> 16));
        }
#pragma unroll
      for (int rg = 0; rg < 4; ++rg) {
        float R   = gv[0][rg] + gv[1][rg] + gv[2][rg] + br;
        float Z   = gv[3][rg] + gv[4][rg] + gv[5][rg] + bz;
        float XNv = gv[6][rg] + bxn;
        float HNv = gv[7][rg] + bhn;
        float r_ = 1.f / (1.f + __expf(-R));
        float z_ = 1.f / (1.f + __expf(-Z));
        float pre = XNv + r_ * HNv;
        float e2 = __expf(2.f * pre);
        float n_ = 1.f - 2.f / (e2 + 1.f);
        float hn_ = (1.f - z_) * n_ + z_ * hold[rg];
        hold[rg] = hn_;
        hbf[(usub * 16 + l4 * 4 + rg) * 40 + uni * 16 + l15] = f2h(hn_);
      }
    }
    __syncthreads();                         // B3: hbf ready

    // ---- write h(t+1) chunk kc=jt (waves 0,1) ----
    if (w < 2) {
      const int row = w * 16 + l15;
      const uint4 hv = *(const uint4*)&hbf[(size_t)row * 40 + l4 * 8];
      u64 lo = ((u64)hv.y << 32) | (u64)hv.x;
      u64 hi = ((u64)hv.w << 32) | (u64)hv.z;
      u64* dst = hbuf + (size_t)((par ^ 1) * MT + m) * HB_U64_PER
                      + ((size_t)(jt * 2 + w) * 64 + l) * 2;
      __hip_atomic_store(dst, lo, __ATOMIC_RELAXED, __HIP_MEMORY_SCOPE_AGENT);
      __hip_atomic_store(dst + 1, hi, __ATOMIC_RELAXED, __HIP_MEMORY_SCOPE_AGENT);
    }
    asm volatile("s_waitcnt vmcnt(0)" ::: "memory");  // h-stores ACKed at LLC
    __syncthreads();                         // B4
    if (tid == 0)
      __hip_atomic_store(fl + jt, (u32)(t + 1), __ATOMIC_RELAXED, __HIP_MEMORY_SCOPE_AGENT);

    // ---- prefetch x(t+1): flies during next wait + h-DMA ----
    if (t + 1 < NT) ISSUE_X(t + 1);
  }
}

// ---------------- logits pass: out[b, s, :] = hs[s] @ Wout^T + bout ----------------
__global__ __launch_bounds__(256, 1)
void logits_pass(const u16* __restrict__ harch, const u64* __restrict__ hbuf,
                 const u16* __restrict__ wopack, const float* __restrict__ bout,
                 float* __restrict__ out) {
  __shared__ uint4 hlds[HKC * 2 * 64];       // 64KB h tile
  __shared__ f32x4 redv[4 * 3 * 64];         // 3KB exchange
  const int bid = blockIdx.x;
  const int m = bid >> 9;                    // 0..7
  const int s = bid & 511;                   // 0..511
  const int tid = threadIdx.x;
  const int w = tid >> 6, l = tid & 63;
  const int l15 = l & 15, l4 = l >> 4;
  const int usub = w >> 1, uni = w & 1;
  const uint4* wo = (const uint4*)wopack;
  const f32x4 z4 = {0.f, 0.f, 0.f, 0.f};

  // stage h tile: slot s<511 from archive, s==511 from hbuf parity 0
  const char* gb = (s < 511)
      ? (const char*)(harch + (size_t)(m * NT + s) * XSLOT_U16)
      : (const char*)(hbuf + (size_t)(0 * MT + m) * HB_U64_PER);
#pragma unroll
  for (int k = 0; k < 16; ++k)
    gll16c(gb + ((size_t)(k * 256 + tid)) * 16, (void*)(hlds + (k * 256 + w * 64)));
  asm volatile("s_waitcnt vmcnt(0)" ::: "memory");
  __syncthreads();

  f32x4 aL[2][2];
  aL[0][0] = z4; aL[0][1] = z4; aL[1][0] = z4; aL[1][1] = z4;
#pragma unroll
  for (int c_ = 0; c_ < 8; ++c_) {
    const int kc_ = w * 8 + c_;
    uint4 A0 = hlds[(kc_ * 2 + 0) * 64 + l];
    uint4 A1 = hlds[(kc_ * 2 + 1) * 64 + l];
    uint4 O0 = wo[(size_t)(kc_ * 2 + 0) * 64 + l];
    uint4 O1 = wo[(size_t)(kc_ * 2 + 1) * 64 + l];
    half8 a0 = __builtin_bit_cast(half8, A0);
    half8 a1 = __builtin_bit_cast(half8, A1);
    half8 o0 = __builtin_bit_cast(half8, O0);
    half8 o1 = __builtin_bit_cast(half8, O1);
    aL[0][0] = MFMA16(a0, o0, aL[0][0]);
    aL[0][1] = MFMA16(a0, o1, aL[0][1]);
    aL[1][0] = MFMA16(a1, o0, aL[1][0]);
    aL[1][1] = MFMA16(a1, o1, aL[1][1]);
  }
  f32x4 sL;
#pragma unroll
  for (int o = 0; o < 4; ++o) {
    if (o == w) sL = aL[usub][uni];
    else {
      const int slot = (w > o) ? (w - 1) : w;
      redv[(o * 3 + slot) * 64 + l] = aL[o >> 1][o & 1];
    }
  }
  __syncthreads();
#pragma unroll
  for (int slot = 0; slot < 3; ++slot)
    sL += redv[(w * 3 + slot) * 64 + l];
  const int col = uni * 16 + l15;
  if (col < NL) {
#pragma unroll
    for (int rg = 0; rg < 4; ++rg) {
      const int row = usub * 16 + l4 * 4 + rg;
      const size_t b_ = (size_t)m * 32 + row;
      out[(b_ * NT + s) * NL + col] = sL[rg] + bout[col];
    }
  }
}

extern "C" void kernel_launch(void* const* d_in, const int* in_sizes, int n_in,
                              void* d_out, int out_size, void* d_ws, size_t ws_size,
                              hipStream_t stream) {
  (void)in_sizes; (void)n_in; (void)out_size;
  const float* seg   = (const float*)d_in[0];
  const int*   labels= (const int*)d_in[1];
  const float* emb   = (const float*)d_in[2];
  const float* Wih   = (const float*)d_in[3];
  const float* Whh   = (const float*)d_in[4];
  const float* bih   = (const float*)d_in[5];
  const float* bhh   = (const float*)d_in[6];
  const float* Wout  = (const float*)d_in[7];
  const float* bout  = (const float*)d_in[8];
  float* out = (float*)d_out;
  char* ws = (char*)d_ws;
  if (ws_size < WS_TOTAL) return;

  zero_ws<<<129, 256, 0, stream>>>((uint4*)(ws + WS_CNT));
  pack_w<<<3280, 256, 0, stream>>>(Wih, Whh, Wout,
                                   (u16*)(ws + WS_WPACK), (u16*)(ws + WS_WOPACK));
  pack_x<<<4096, 256, 0, stream>>>(seg, labels, emb, (u16*)(ws + WS_XPACK));
  gru_persist<<<NBLK, THREADS, 0, stream>>>(
      (u16*)(ws + WS_XPACK), (const u16*)(ws + WS_WPACK), bih, bhh,
      (u64*)(ws + WS_HBUF), (u32*)(ws + WS_CNT));
  logits_pass<<<MT * NT, 256, 0, stream>>>(
      (const u16*)(ws + WS_XPACK), (const u64*)(ws + WS_HBUF),
      (const u16*)(ws + WS_WOPACK), bout, out);
}

// Round 18
// 4510.065 us; speedup vs baseline: 1.6543x; 1.0044x over previous
//
#include <hip/hip_runtime.h>
#include <hip/hip_fp16.h>

typedef unsigned short u16;
typedef unsigned int u32;
typedef unsigned long long u64;

#define NT 512      // time steps
#define NB 256      // batch
#define NH 1024     // hidden
#define NE 128      // emb dim
#define NHE 1152    // H+E
#define NL 17       // labels
#define MT 8        // batch groups (32 rows each)
#define JTILES 32   // hidden-col tiles (32 cols each)
#define XKC 36      // K-chunks (32 wide) for x part
#define HKC 32      // K-chunks for h part
#define KCT 68      // XKC + HKC
#define NBLK 256    // MT * JTILES
#define THREADS 512 // 8 waves, k-split across gates

typedef __attribute__((ext_vector_type(8))) _Float16 half8;
typedef __attribute__((ext_vector_type(4))) float f32x4;

// ---- workspace layout (bytes) ----
#define WS_CNT     0ull
#define WS_HBUF    4096ull
#define WS_WPACK   1052672ull                // 32*68*6*1024     = 13,369,344
#define WS_WOPACK  14422016ull               // 32*2*1024        = 65,536
#define WS_XPACK   14487552ull               // 8*512*36*2*64*16 = 301,989,888
#define WS_TOTAL   316477440ull

#define HB_U64_PER (HKC * 2 * 64 * 2)        // 8192 u64 per (par,m)
#define XSLOT_U16  (XKC * 2 * 64 * 8)        // 36864 u16 per (m,t) x slot (73728B)

__device__ __forceinline__ u16 f2h(float f) {
  __half h = __float2half(f);
  return __builtin_bit_cast(u16, h);
}
__device__ __forceinline__ float h2f(u16 u) {
  return __half2float(__builtin_bit_cast(__half, u));
}
__device__ __forceinline__ uint4 pack8h(const u16* o) {
  uint4 v;
  v.x = (u32)o[0] | ((u32)o[1] << 16);
  v.y = (u32)o[2] | ((u32)o[3] << 16);
  v.z = (u32)o[4] | ((u32)o[5] << 16);
  v.w = (u32)o[6] | ((u32)o[7] << 16);
  return v;
}

// global->LDS DMA, 16B/lane. aux=17 (sc0|sc1): coherent LLC read (h handoff).
__device__ __forceinline__ void gll16u(const void* g, void* l) {
  __builtin_amdgcn_global_load_lds((const __attribute__((address_space(1))) u32*)g,
                                   (__attribute__((address_space(3))) u32*)l, 16, 0, 17);
}
// aux=0: normal cached read (x stream; shared via L2/L3).
__device__ __forceinline__ void gll16c(const void* g, void* l) {
  __builtin_amdgcn_global_load_lds((const __attribute__((address_space(1))) u32*)g,
                                   (__attribute__((address_space(3))) u32*)l, 16, 0, 0);
}

// ---------------- zero flags + h parity-0 ----------------
__global__ void zero_ws(uint4* p) {
  int idx = blockIdx.x * 256 + threadIdx.x;
  if (idx < 33024) {
    uint4 z; z.x = 0; z.y = 0; z.z = 0; z.w = 0;
    p[idx] = z;
  }
}

// ---------------- pack weights into B-fragment order ----------------
__global__ void pack_w(const float* __restrict__ Wih, const float* __restrict__ Whh,
                       const float* __restrict__ Wout, u16* __restrict__ wpack,
                       u16* __restrict__ wopack) {
  int idx = blockIdx.x * 256 + threadIdx.x;
  const int WUNITS = JTILES * KCT * 3 * 2 * 64;   // 835584
  if (idx < WUNITS) {
    int l = idx & 63;
    int r = idx >> 6;
    int ni = r & 1; r >>= 1;
    int g = r % 3;  r /= 3;
    int kc = r % KCT; r /= KCT;
    int jt = r;
    int row = g * NH + jt * 32 + ni * 16 + (l & 15);
    int kk = (l >> 4) * 8;
    const float* src = (kc < XKC) ? (Wih + (size_t)row * NHE + kc * 32 + kk)
                                  : (Whh + (size_t)row * NH + (kc - XKC) * 32 + kk);
    u16 o[8];
#pragma unroll
    for (int e = 0; e < 8; ++e) o[e] = f2h(src[e]);
    ((uint4*)wpack)[idx] = pack8h(o);
  } else if (idx < WUNITS + HKC * 2 * 64) {
    int j = idx - WUNITS;
    int l = j & 63; j >>= 6;
    int ni = j & 1; int kc = j >> 1;
    int col = (l & 15) + 16 * ni;
    int kk = kc * 32 + (l >> 4) * 8;
    u16 o[8];
#pragma unroll
    for (int e = 0; e < 8; ++e)
      o[e] = (col < NL) ? f2h(Wout[(size_t)col * NH + kk + e]) : (u16)0;
    ((uint4*)wopack)[idx - WUNITS] = pack8h(o);
  }
}

// ---------------- pack x = [seg | emb(prev)] into A-fragment order ----------------
__global__ void pack_x(const float* __restrict__ seg, const int* __restrict__ labels,
                       const float* __restrict__ emb, u16* __restrict__ xpack) {
  __shared__ float ls[32][65];
  __shared__ int lbl[32];
  const int bid = blockIdx.x;
  const int t = bid & (NT - 1);
  const int m = bid >> 9;                    // 0..7
  const int tid = threadIdx.x;
  u16* outb = xpack + (size_t)(m * NT + t) * XSLOT_U16;
  const int r = tid >> 3, qq = tid & 7;      // 32 rows x 8 col-chunks
  const int l = tid & 63;

  for (int kc2 = 0; kc2 < 16; ++kc2) {       // stage 64 cols of seg at a time
    const float* s = seg + ((size_t)(m * 32 + r) * NT + t) * NH + kc2 * 64 + qq * 8;
    float4 a = ((const float4*)s)[0];
    float4 b2 = ((const float4*)s)[1];
    ls[r][qq * 8 + 0] = a.x;  ls[r][qq * 8 + 1] = a.y;
    ls[r][qq * 8 + 2] = a.z;  ls[r][qq * 8 + 3] = a.w;
    ls[r][qq * 8 + 4] = b2.x; ls[r][qq * 8 + 5] = b2.y;
    ls[r][qq * 8 + 6] = b2.z; ls[r][qq * 8 + 7] = b2.w;
    __syncthreads();
    const int sub2 = tid >> 6;               // 0..3 -> (kc half, sub)
    const int kc = kc2 * 2 + (sub2 >> 1);
    const int sub = sub2 & 1;
    const int row = sub * 16 + (l & 15);
    const int c0 = (sub2 >> 1) * 32 + (l >> 4) * 8;
    u16 o[8];
#pragma unroll
    for (int e = 0; e < 8; ++e) o[e] = f2h(ls[row][c0 + e]);
    ((uint4*)outb)[(kc * 2 + sub) * 64 + l] = pack8h(o);
    __syncthreads();
  }
  if (tid < 32)
    lbl[tid] = (t == 0) ? NL : labels[(size_t)(m * 32 + tid) * NT + (t - 1)];
  __syncthreads();
#pragma unroll
  for (int k = 0; k < 2; ++k) {
    int u = tid + k * 256;                   // 512 units: kc 32..35, sub, l
    int kc = 32 + (u >> 7);
    int sub = (u >> 6) & 1;
    int ll = u & 63;
    int row = sub * 16 + (ll & 15);
    int c = (kc - 32) * 32 + (ll >> 4) * 8;
    const float* s = emb + (size_t)lbl[row] * NE + c;
    float4 a = ((const float4*)s)[0];
    float4 b2 = ((const float4*)s)[1];
    u16 o[8];
    o[0] = f2h(a.x); o[1] = f2h(a.y); o[2] = f2h(a.z); o[3] = f2h(a.w);
    o[4] = f2h(b2.x); o[5] = f2h(b2.y); o[6] = f2h(b2.z); o[7] = f2h(b2.w);
    ((uint4*)outb)[(kc * 2 + sub) * 64 + ll] = pack8h(o);
  }
}

// ---------------- persistent GRU kernel ----------------
#define MFMA16(a, b, c) __builtin_amdgcn_mfma_f32_16x16x32_f16((a), (b), (c), 0, 0, 0)

// all-lane wait with throttled polling: s_sleep(2) (~128cy) between polls cuts
// LLC poll traffic on the hot flag lines during the producer's store window.
#define WAIT_FLAGS(tgt) do { \
  while (true) { \
    u32 v_ = __hip_atomic_load(fl + (l & 31), __ATOMIC_RELAXED, __HIP_MEMORY_SCOPE_AGENT); \
    if (__all((int)v_ >= (tgt))) break; \
    __builtin_amdgcn_s_sleep(2); \
  } \
} while (0)

// issue x(tt) DMA into xlds (not drained here): 4608 units / 512 threads = 9
#define ISSUE_X(tt) do { \
  const char* xgb_ = (const char*)xpack + (size_t)(m * NT + (tt)) * (XSLOT_U16 * 2); \
  _Pragma("unroll") \
  for (int k_ = 0; k_ < 9; ++k_) \
    gll16c(xgb_ + ((size_t)(k_ * 512 + tid)) * 16, (void*)(xlds + (k_ * 512 + w * 64))); \
} while (0)

__global__ __launch_bounds__(THREADS, 1)
void gru_persist(u16* xpack, const u16* __restrict__ wpack,
                 const float* __restrict__ bih, const float* __restrict__ bhh,
                 u64* __restrict__ hbuf, u32* __restrict__ counters) {
  __shared__ uint4 hlds[HKC * 2 * 64];           // 64KB h(t) tile (frag-linear)
  __shared__ uint4 xlds[XKC * 2 * 64];           // 72KB x(t) tile (frag-linear)
  __shared__ u32 glds16[8 * 2 * 2 * 2 * 64];     // 16KB fp16 gate partials (8 tasks)
  __shared__ u16 hbf[32 * 40];                   // 2.5KB fp16 bounce

  const int bid = blockIdx.x;
  const int xcd = bid & 7;
  const int q = bid >> 3;
  const int m = q & 7;
  const int jslot = q >> 3;
  const int jt = jslot * 8 + xcd;            // weights L2-resident per XCD
  const int tid = threadIdx.x;
  const int w = tid >> 6, l = tid & 63;
  const int l15 = l & 15, l4 = l >> 4;
  const int usub = (w >> 1) & 1, uni = w & 1; // update subtile for waves 0-3

  const uint4* wp = (const uint4*)wpack;
  u32* fl = counters + m * 64;               // 32 flags per group
  const size_t wbase_u = (size_t)jt * (KCT * 6 * 64);

  const int ocol = jt * 32 + uni * 16 + l15;
  const float br = bih[ocol] + bhh[ocol];
  const float bz = bih[NH + ocol] + bhh[NH + ocol];
  const float bxn = bih[2 * NH + ocol];
  const float bhn = bhh[2 * NH + ocol];
  float hold[4] = {0.f, 0.f, 0.f, 0.f};
  const f32x4 z4 = {0.f, 0.f, 0.f, 0.f};

  // wave task table: w0,w1,w2 -> R(x1,x2,h); w3,w4,w5 -> Z(x1,x2,h);
  // w6 -> XN(x); w7 -> HN(h). max 36 kc per wave.
  int tg, tkc0, tkcn; bool tIsX;
  if (w == 6)      { tg = 2; tIsX = true;  tkc0 = 0;  tkcn = 36; }
  else if (w == 7) { tg = 2; tIsX = false; tkc0 = 0;  tkcn = 32; }
  else {
    tg = (w < 3) ? 0 : 1;
    const int r_ = (w < 3) ? w : (w - 3);
    tIsX = (r_ < 2);
    tkc0 = (r_ == 1) ? 18 : 0;
    tkcn = tIsX ? ((r_ == 0) ? 18 : 36) : 32;
  }
  const int tkadd = tIsX ? 0 : XKC;          // kc -> wpack kc index offset
  const uint4* asrc = tIsX ? xlds : hlds;

  // archive-store thread mapping (2KB chunk jt of hlds -> dead xpack slot)
  const int a_sub = (tid >> 7) & 1, a_half = (tid >> 6) & 1, a_l = tid & 63;
  const size_t a_off = ((size_t)(jt * 2 + a_sub) * 64 + a_l) * 2 + a_half;

  // ---- prologue: issue x(0) ----
  ISSUE_X(0);

  for (int t = 0; t < NT; ++t) {
    const int par = t & 1;

    // ---- wait for group's h(t) (x(t) DMA already in flight) ----
    WAIT_FLAGS(t);

    // ---- DMA h(t) (coherent LLC); drain x+h together ----
    {
      const char* gb = (const char*)hbuf + ((size_t)(par * MT + m) * HB_U64_PER) * 8;
#pragma unroll
      for (int k = 0; k < 8; ++k)
        gll16u(gb + ((size_t)(k * 512 + tid)) * 16, (void*)(hlds + (k * 512 + w * 64)));
      asm volatile("s_waitcnt vmcnt(0)" ::: "memory");
      __syncthreads();                       // B1: hlds + xlds ready
    }

    // ---- archive h(t) chunk jt into dead xpack slot (m, t-1) ----
    if (t > 0 && tid < 256) {
      const u64 v = ((const u64*)hlds)[a_off];
      u64* dst = (u64*)(xpack + (size_t)(m * NT + (t - 1)) * XSLOT_U16);
      dst[a_off] = v;
    }

    // ---- MFMA phase: wave's (gate, k-range) task ----
    f32x4 acc[2][2];
    acc[0][0] = z4; acc[0][1] = z4; acc[1][0] = z4; acc[1][1] = z4;
#pragma unroll 4
    for (int kc = tkc0; kc < tkcn; ++kc) {
      const int kcw = kc + tkadd;
      uint4 A0 = asrc[(kc * 2 + 0) * 64 + l];
      uint4 A1 = asrc[(kc * 2 + 1) * 64 + l];
      uint4 B0 = wp[wbase_u + (size_t)((kcw * 3 + tg) * 2 + 0) * 64 + l];
      uint4 B1 = wp[wbase_u + (size_t)((kcw * 3 + tg) * 2 + 1) * 64 + l];
      half8 a0 = __builtin_bit_cast(half8, A0);
      half8 a1 = __builtin_bit_cast(half8, A1);
      half8 b0 = __builtin_bit_cast(half8, B0);
      half8 b1 = __builtin_bit_cast(half8, B1);
      acc[0][0] = MFMA16(a0, b0, acc[0][0]);
      acc[0][1] = MFMA16(a0, b1, acc[0][1]);
      acc[1][0] = MFMA16(a1, b0, acc[1][0]);
      acc[1][1] = MFMA16(a1, b1, acc[1][1]);
    }

    // ---- publish fp16 partial tiles (task w) ----
#pragma unroll
    for (int s = 0; s < 2; ++s)
#pragma unroll
      for (int n = 0; n < 2; ++n)
#pragma unroll
        for (int rgp = 0; rgp < 2; ++rgp) {
          u32 v = (u32)f2h(acc[s][n][rgp * 2]) |
                  ((u32)f2h(acc[s][n][rgp * 2 + 1]) << 16);
          glds16[((((w * 2 + s) * 2 + n) * 2 + rgp)) * 64 + l] = v;
        }
    __syncthreads();                         // B2: all partials + xlds reads done

    // ---- gate math (waves 0-3 own subtiles) ----
    if (w < 4) {
      float gv[8][4];
#pragma unroll
      for (int task = 0; task < 8; ++task)
#pragma unroll
        for (int rgp = 0; rgp < 2; ++rgp) {
          u32 v = glds16[((((task * 2 + usub) * 2 + uni) * 2 + rgp)) * 64 + l];
          gv[task][rgp * 2]     = h2f((u16)v);
          gv[task][rgp * 2 + 1] = h2f((u16)(v >> 16));
        }
#pragma unroll
      for (int rg = 0; rg < 4; ++rg) {
        float R   = gv[0][rg] + gv[1][rg] + gv[2][rg] + br;
        float Z   = gv[3][rg] + gv[4][rg] + gv[5][rg] + bz;
        float XNv = gv[6][rg] + bxn;
        float HNv = gv[7][rg] + bhn;
        float r_ = 1.f / (1.f + __expf(-R));
        float z_ = 1.f / (1.f + __expf(-Z));
        float pre = XNv + r_ * HNv;
        float e2 = __expf(2.f * pre);
        float n_ = 1.f - 2.f / (e2 + 1.f);
        float hn_ = (1.f - z_) * n_ + z_ * hold[rg];
        hold[rg] = hn_;
        hbf[(usub * 16 + l4 * 4 + rg) * 40 + uni * 16 + l15] = f2h(hn_);
      }
    }
    __syncthreads();                         // B3: hbf ready

    // ---- write h(t+1) chunk kc=jt (waves 0,1) ----
    if (w < 2) {
      const int row = w * 16 + l15;
      const uint4 hv = *(const uint4*)&hbf[(size_t)row * 40 + l4 * 8];
      u64 lo = ((u64)hv.y << 32) | (u64)hv.x;
      u64 hi = ((u64)hv.w << 32) | (u64)hv.z;
      u64* dst = hbuf + (size_t)((par ^ 1) * MT + m) * HB_U64_PER
                      + ((size_t)(jt * 2 + w) * 64 + l) * 2;
      __hip_atomic_store(dst, lo, __ATOMIC_RELAXED, __HIP_MEMORY_SCOPE_AGENT);
      __hip_atomic_store(dst + 1, hi, __ATOMIC_RELAXED, __HIP_MEMORY_SCOPE_AGENT);
    }
    asm volatile("s_waitcnt vmcnt(0)" ::: "memory");  // h-stores ACKed at LLC
    __syncthreads();                         // B4
    if (tid == 0)
      __hip_atomic_store(fl + jt, (u32)(t + 1), __ATOMIC_RELAXED, __HIP_MEMORY_SCOPE_AGENT);

    // ---- prefetch x(t+1): flies during next wait + h-DMA ----
    if (t + 1 < NT) ISSUE_X(t + 1);
  }
}

// ---------------- logits pass: out[b, s, :] = hs[s] @ Wout^T + bout ----------------
__global__ __launch_bounds__(256, 1)
void logits_pass(const u16* __restrict__ harch, const u64* __restrict__ hbuf,
                 const u16* __restrict__ wopack, const float* __restrict__ bout,
                 float* __restrict__ out) {
  __shared__ uint4 hlds[HKC * 2 * 64];       // 64KB h tile
  __shared__ f32x4 redv[4 * 3 * 64];         // 3KB exchange
  const int bid = blockIdx.x;
  const int m = bid >> 9;                    // 0..7
  const int s = bid & 511;                   // 0..511
  const int tid = threadIdx.x;
  const int w = tid >> 6, l = tid & 63;
  const int l15 = l & 15, l4 = l >> 4;
  const int usub = w >> 1, uni = w & 1;
  const uint4* wo = (const uint4*)wopack;
  const f32x4 z4 = {0.f, 0.f, 0.f, 0.f};

  // stage h tile: slot s<511 from archive, s==511 from hbuf parity 0
  const char* gb = (s < 511)
      ? (const char*)(harch + (size_t)(m * NT + s) * XSLOT_U16)
      : (const char*)(hbuf + (size_t)(0 * MT + m) * HB_U64_PER);
#pragma unroll
  for (int k = 0; k < 16; ++k)
    gll16c(gb + ((size_t)(k * 256 + tid)) * 16, (void*)(hlds + (k * 256 + w * 64)));
  asm volatile("s_waitcnt vmcnt(0)" ::: "memory");
  __syncthreads();

  f32x4 aL[2][2];
  aL[0][0] = z4; aL[0][1] = z4; aL[1][0] = z4; aL[1][1] = z4;
#pragma unroll
  for (int c_ = 0; c_ < 8; ++c_) {
    const int kc_ = w * 8 + c_;
    uint4 A0 = hlds[(kc_ * 2 + 0) * 64 + l];
    uint4 A1 = hlds[(kc_ * 2 + 1) * 64 + l];
    uint4 O0 = wo[(size_t)(kc_ * 2 + 0) * 64 + l];
    uint4 O1 = wo[(size_t)(kc_ * 2 + 1) * 64 + l];
    half8 a0 = __builtin_bit_cast(half8, A0);
    half8 a1 = __builtin_bit_cast(half8, A1);
    half8 o0 = __builtin_bit_cast(half8, O0);
    half8 o1 = __builtin_bit_cast(half8, O1);
    aL[0][0] = MFMA16(a0, o0, aL[0][0]);
    aL[0][1] = MFMA16(a0, o1, aL[0][1]);
    aL[1][0] = MFMA16(a1, o0, aL[1][0]);
    aL[1][1] = MFMA16(a1, o1, aL[1][1]);
  }
  f32x4 sL;
#pragma unroll
  for (int o = 0; o < 4; ++o) {
    if (o == w) sL = aL[usub][uni];
    else {
      const int slot = (w > o) ? (w - 1) : w;
      redv[(o * 3 + slot) * 64 + l] = aL[o >> 1][o & 1];
    }
  }
  __syncthreads();
#pragma unroll
  for (int slot = 0; slot < 3; ++slot)
    sL += redv[(w * 3 + slot) * 64 + l];
  const int col = uni * 16 + l15;
  if (col < NL) {
#pragma unroll
    for (int rg = 0; rg < 4; ++rg) {
      const int row = usub * 16 + l4 * 4 + rg;
      const size_t b_ = (size_t)m * 32 + row;
      out[(b_ * NT + s) * NL + col] = sL[rg] + bout[col];
    }
  }
}

extern "C" void kernel_launch(void* const* d_in, const int* in_sizes, int n_in,
                              void* d_out, int out_size, void* d_ws, size_t ws_size,
                              hipStream_t stream) {
  (void)in_sizes; (void)n_in; (void)out_size;
  const float* seg   = (const float*)d_in[0];
  const int*   labels= (const int*)d_in[1];
  const float* emb   = (const float*)d_in[2];
  const float* Wih   = (const float*)d_in[3];
  const float* Whh   = (const float*)d_in[4];
  const float* bih   = (const float*)d_in[5];
  const float* bhh   = (const float*)d_in[6];
  const float* Wout  = (const float*)d_in[7];
  const float* bout  = (const float*)d_in[8];
  float* out = (float*)d_out;
  char* ws = (char*)d_ws;
  if (ws_size < WS_TOTAL) return;

  zero_ws<<<129, 256, 0, stream>>>((uint4*)(ws + WS_CNT));
  pack_w<<<3280, 256, 0, stream>>>(Wih, Whh, Wout,
                                   (u16*)(ws + WS_WPACK), (u16*)(ws + WS_WOPACK));
  pack_x<<<4096, 256, 0, stream>>>(seg, labels, emb, (u16*)(ws + WS_XPACK));
  gru_persist<<<NBLK, THREADS, 0, stream>>>(
      (u16*)(ws + WS_XPACK), (const u16*)(ws + WS_WPACK), bih, bhh,
      (u64*)(ws + WS_HBUF), (u32*)(ws + WS_CNT));
  logits_pass<<<MT * NT, 256, 0, stream>>>(
      (const u16*)(ws + WS_XPACK), (const u64*)(ws + WS_HBUF),
      (const u16*)(ws + WS_WOPACK), bout, out);
}

// Round 19
// 4017.311 us; speedup vs baseline: 1.8572x; 1.1227x over previous
//
#include <hip/hip_runtime.h>
#include <hip/hip_fp16.h>

typedef unsigned short u16;
typedef unsigned int u32;
typedef unsigned long long u64;

#define NT 512      // time steps
#define NB 256      // batch
#define NH 1024     // hidden
#define NE 128      // emb dim
#define NHE 1152    // H+E
#define NL 17       // labels
#define MT 8        // batch groups (32 rows each)
#define JTILES 32   // hidden-col tiles (32 cols each)
#define XKC 36      // K-chunks (32 wide) for x part
#define HKC 32      // K-chunks for h part
#define KCT 68      // XKC + HKC
#define NBLK 256    // MT * JTILES
#define THREADS 512 // 8 waves, k-split across gates
#define NC 14       // B kc-units register-cached per wave (loop-invariant)

typedef __attribute__((ext_vector_type(8))) _Float16 half8;
typedef __attribute__((ext_vector_type(4))) float f32x4;

// ---- workspace layout (bytes) ----
#define WS_CNT     0ull
#define WS_HBUF    4096ull
#define WS_WPACK   1052672ull                // 32*68*6*1024     = 13,369,344
#define WS_WOPACK  14422016ull               // 32*2*1024        = 65,536
#define WS_XPACK   14487552ull               // 8*512*36*2*64*16 = 301,989,888
#define WS_TOTAL   316477440ull

#define HB_U64_PER (HKC * 2 * 64 * 2)        // 8192 u64 per (par,m)
#define XSLOT_U16  (XKC * 2 * 64 * 8)        // 36864 u16 per (m,t) x slot (73728B)

__device__ __forceinline__ u16 f2h(float f) {
  __half h = __float2half(f);
  return __builtin_bit_cast(u16, h);
}
__device__ __forceinline__ float h2f(u16 u) {
  return __half2float(__builtin_bit_cast(__half, u));
}
__device__ __forceinline__ uint4 pack8h(const u16* o) {
  uint4 v;
  v.x = (u32)o[0] | ((u32)o[1] << 16);
  v.y = (u32)o[2] | ((u32)o[3] << 16);
  v.z = (u32)o[4] | ((u32)o[5] << 16);
  v.w = (u32)o[6] | ((u32)o[7] << 16);
  return v;
}

// global->LDS DMA, 16B/lane. aux=17 (sc0|sc1): coherent LLC read (h handoff).
__device__ __forceinline__ void gll16u(const void* g, void* l) {
  __builtin_amdgcn_global_load_lds((const __attribute__((address_space(1))) u32*)g,
                                   (__attribute__((address_space(3))) u32*)l, 16, 0, 17);
}
// aux=0: normal cached read (x stream; shared via L2/L3).
__device__ __forceinline__ void gll16c(const void* g, void* l) {
  __builtin_amdgcn_global_load_lds((const __attribute__((address_space(1))) u32*)g,
                                   (__attribute__((address_space(3))) u32*)l, 16, 0, 0);
}

// ---------------- zero flags + h parity-0 ----------------
__global__ void zero_ws(uint4* p) {
  int idx = blockIdx.x * 256 + threadIdx.x;
  if (idx < 33024) {
    uint4 z; z.x = 0; z.y = 0; z.z = 0; z.w = 0;
    p[idx] = z;
  }
}

// ---------------- pack weights into B-fragment order ----------------
__global__ void pack_w(const float* __restrict__ Wih, const float* __restrict__ Whh,
                       const float* __restrict__ Wout, u16* __restrict__ wpack,
                       u16* __restrict__ wopack) {
  int idx = blockIdx.x * 256 + threadIdx.x;
  const int WUNITS = JTILES * KCT * 3 * 2 * 64;   // 835584
  if (idx < WUNITS) {
    int l = idx & 63;
    int r = idx >> 6;
    int ni = r & 1; r >>= 1;
    int g = r % 3;  r /= 3;
    int kc = r % KCT; r /= KCT;
    int jt = r;
    int row = g * NH + jt * 32 + ni * 16 + (l & 15);
    int kk = (l >> 4) * 8;
    const float* src = (kc < XKC) ? (Wih + (size_t)row * NHE + kc * 32 + kk)
                                  : (Whh + (size_t)row * NH + (kc - XKC) * 32 + kk);
    u16 o[8];
#pragma unroll
    for (int e = 0; e < 8; ++e) o[e] = f2h(src[e]);
    ((uint4*)wpack)[idx] = pack8h(o);
  } else if (idx < WUNITS + HKC * 2 * 64) {
    int j = idx - WUNITS;
    int l = j & 63; j >>= 6;
    int ni = j & 1; int kc = j >> 1;
    int col = (l & 15) + 16 * ni;
    int kk = kc * 32 + (l >> 4) * 8;
    u16 o[8];
#pragma unroll
    for (int e = 0; e < 8; ++e)
      o[e] = (col < NL) ? f2h(Wout[(size_t)col * NH + kk + e]) : (u16)0;
    ((uint4*)wopack)[idx - WUNITS] = pack8h(o);
  }
}

// ---------------- pack x = [seg | emb(prev)] into A-fragment order ----------------
__global__ void pack_x(const float* __restrict__ seg, const int* __restrict__ labels,
                       const float* __restrict__ emb, u16* __restrict__ xpack) {
  __shared__ float ls[32][65];
  __shared__ int lbl[32];
  const int bid = blockIdx.x;
  const int t = bid & (NT - 1);
  const int m = bid >> 9;                    // 0..7
  const int tid = threadIdx.x;
  u16* outb = xpack + (size_t)(m * NT + t) * XSLOT_U16;
  const int r = tid >> 3, qq = tid & 7;      // 32 rows x 8 col-chunks
  const int l = tid & 63;

  for (int kc2 = 0; kc2 < 16; ++kc2) {       // stage 64 cols of seg at a time
    const float* s = seg + ((size_t)(m * 32 + r) * NT + t) * NH + kc2 * 64 + qq * 8;
    float4 a = ((const float4*)s)[0];
    float4 b2 = ((const float4*)s)[1];
    ls[r][qq * 8 + 0] = a.x;  ls[r][qq * 8 + 1] = a.y;
    ls[r][qq * 8 + 2] = a.z;  ls[r][qq * 8 + 3] = a.w;
    ls[r][qq * 8 + 4] = b2.x; ls[r][qq * 8 + 5] = b2.y;
    ls[r][qq * 8 + 6] = b2.z; ls[r][qq * 8 + 7] = b2.w;
    __syncthreads();
    const int sub2 = tid >> 6;               // 0..3 -> (kc half, sub)
    const int kc = kc2 * 2 + (sub2 >> 1);
    const int sub = sub2 & 1;
    const int row = sub * 16 + (l & 15);
    const int c0 = (sub2 >> 1) * 32 + (l >> 4) * 8;
    u16 o[8];
#pragma unroll
    for (int e = 0; e < 8; ++e) o[e] = f2h(ls[row][c0 + e]);
    ((uint4*)outb)[(kc * 2 + sub) * 64 + l] = pack8h(o);
    __syncthreads();
  }
  if (tid < 32)
    lbl[tid] = (t == 0) ? NL : labels[(size_t)(m * 32 + tid) * NT + (t - 1)];
  __syncthreads();
#pragma unroll
  for (int k = 0; k < 2; ++k) {
    int u = tid + k * 256;                   // 512 units: kc 32..35, sub, l
    int kc = 32 + (u >> 7);
    int sub = (u >> 6) & 1;
    int ll = u & 63;
    int row = sub * 16 + (ll & 15);
    int c = (kc - 32) * 32 + (ll >> 4) * 8;
    const float* s = emb + (size_t)lbl[row] * NE + c;
    float4 a = ((const float4*)s)[0];
    float4 b2 = ((const float4*)s)[1];
    u16 o[8];
    o[0] = f2h(a.x); o[1] = f2h(a.y); o[2] = f2h(a.z); o[3] = f2h(a.w);
    o[4] = f2h(b2.x); o[5] = f2h(b2.y); o[6] = f2h(b2.z); o[7] = f2h(b2.w);
    ((uint4*)outb)[(kc * 2 + sub) * 64 + ll] = pack8h(o);
  }
}

// ---------------- persistent GRU kernel ----------------
#define MFMA16(a, b, c) __builtin_amdgcn_mfma_f32_16x16x32_f16((a), (b), (c), 0, 0, 0)

// all-lane wait with throttled polling
#define WAIT_FLAGS(tgt) do { \
  while (true) { \
    u32 v_ = __hip_atomic_load(fl + (l & 31), __ATOMIC_RELAXED, __HIP_MEMORY_SCOPE_AGENT); \
    if (__all((int)v_ >= (tgt))) break; \
    __builtin_amdgcn_s_sleep(2); \
  } \
} while (0)

// issue x(tt) DMA into xlds (not drained here): 4608 units / 512 threads = 9
#define ISSUE_X(tt) do { \
  const char* xgb_ = (const char*)xpack + (size_t)(m * NT + (tt)) * (XSLOT_U16 * 2); \
  _Pragma("unroll") \
  for (int k_ = 0; k_ < 9; ++k_) \
    gll16c(xgb_ + ((size_t)(k_ * 512 + tid)) * 16, (void*)(xlds + (k_ * 512 + w * 64))); \
} while (0)

// one MFMA kc-step given A-src index and B fragments
#define MFMA_STEP(kcA, B0h, B1h) do { \
  uint4 A0 = asrc[((kcA) * 2 + 0) * 64 + l]; \
  uint4 A1 = asrc[((kcA) * 2 + 1) * 64 + l]; \
  half8 a0 = __builtin_bit_cast(half8, A0); \
  half8 a1 = __builtin_bit_cast(half8, A1); \
  acc[0][0] = MFMA16(a0, (B0h), acc[0][0]); \
  acc[0][1] = MFMA16(a0, (B1h), acc[0][1]); \
  acc[1][0] = MFMA16(a1, (B0h), acc[1][0]); \
  acc[1][1] = MFMA16(a1, (B1h), acc[1][1]); \
} while (0)

__global__ __launch_bounds__(THREADS, 1)
void gru_persist(u16* xpack, const u16* __restrict__ wpack,
                 const float* __restrict__ bih, const float* __restrict__ bhh,
                 u64* __restrict__ hbuf, u32* __restrict__ counters) {
  __shared__ uint4 hlds[HKC * 2 * 64];           // 64KB h(t) tile (frag-linear)
  __shared__ uint4 xlds[XKC * 2 * 64];           // 72KB x(t) tile (frag-linear)
  __shared__ u32 glds16[8 * 2 * 2 * 2 * 64];     // 16KB fp16 gate partials (8 tasks)
  __shared__ u16 hbf[32 * 40];                   // 2.5KB fp16 bounce

  const int bid = blockIdx.x;
  const int xcd = bid & 7;
  const int q = bid >> 3;
  const int m = q & 7;
  const int jslot = q >> 3;
  const int jt = jslot * 8 + xcd;            // weights L2-resident per XCD
  const int tid = threadIdx.x;
  const int w = tid >> 6, l = tid & 63;
  const int l15 = l & 15, l4 = l >> 4;
  const int usub = (w >> 1) & 1, uni = w & 1; // update subtile for waves 0-3

  const uint4* wp = (const uint4*)wpack;
  u32* fl = counters + m * 64;               // 32 flags per group
  const size_t wbase_u = (size_t)jt * (KCT * 6 * 64);

  const int ocol = jt * 32 + uni * 16 + l15;
  const float br = bih[ocol] + bhh[ocol];
  const float bz = bih[NH + ocol] + bhh[NH + ocol];
  const float bxn = bih[2 * NH + ocol];
  const float bhn = bhh[2 * NH + ocol];
  float hold[4] = {0.f, 0.f, 0.f, 0.f};
  const f32x4 z4 = {0.f, 0.f, 0.f, 0.f};

  // wave task table: w0,w1,w2 -> R(x1,x2,h); w3,w4,w5 -> Z(x1,x2,h);
  // w6 -> XN(x); w7 -> HN(h). max 36 kc per wave.
  int tg, tkc0, tkcn; bool tIsX;
  if (w == 6)      { tg = 2; tIsX = true;  tkc0 = 0;  tkcn = 36; }
  else if (w == 7) { tg = 2; tIsX = false; tkc0 = 0;  tkcn = 32; }
  else {
    tg = (w < 3) ? 0 : 1;
    const int r_ = (w < 3) ? w : (w - 3);
    tIsX = (r_ < 2);
    tkc0 = (r_ == 1) ? 18 : 0;
    tkcn = tIsX ? ((r_ == 0) ? 18 : 36) : 32;
  }
  const int tkadd = tIsX ? 0 : XKC;          // kc -> wpack kc index offset
  const uint4* asrc = tIsX ? xlds : hlds;

  // archive-store thread mapping (2KB chunk jt of hlds -> dead xpack slot)
  const int a_sub = (tid >> 7) & 1, a_half = (tid >> 6) & 1, a_l = tid & 63;
  const size_t a_off = ((size_t)(jt * 2 + a_sub) * 64 + a_l) * 2 + a_half;

  // ---- register-cache the first NC kc of this wave's B slice (loop-invariant)
  // statically indexed; 112 VGPRs; all tasks have tkcn-tkc0 >= 18 > NC
  half8 BcL[NC], BcH[NC];
#pragma unroll
  for (int j = 0; j < NC; ++j) {
    const int kcw = tkc0 + j + tkadd;
    BcL[j] = __builtin_bit_cast(half8, wp[wbase_u + (size_t)((kcw * 3 + tg) * 2 + 0) * 64 + l]);
    BcH[j] = __builtin_bit_cast(half8, wp[wbase_u + (size_t)((kcw * 3 + tg) * 2 + 1) * 64 + l]);
  }

  // ---- prologue: issue x(0) ----
  ISSUE_X(0);

  for (int t = 0; t < NT; ++t) {
    const int par = t & 1;

    // ---- wait for group's h(t) (x(t) DMA already in flight) ----
    WAIT_FLAGS(t);

    // ---- DMA h(t) (coherent LLC); drain x+h together ----
    {
      const char* gb = (const char*)hbuf + ((size_t)(par * MT + m) * HB_U64_PER) * 8;
#pragma unroll
      for (int k = 0; k < 8; ++k)
        gll16u(gb + ((size_t)(k * 512 + tid)) * 16, (void*)(hlds + (k * 512 + w * 64)));
      asm volatile("s_waitcnt vmcnt(0)" ::: "memory");
      __syncthreads();                       // B1: hlds + xlds ready
    }

    // ---- archive h(t) chunk jt into dead xpack slot (m, t-1) ----
    if (t > 0 && tid < 256) {
      const u64 v = ((const u64*)hlds)[a_off];
      u64* dst = (u64*)(xpack + (size_t)(m * NT + (t - 1)) * XSLOT_U16);
      dst[a_off] = v;
    }

    // ---- MFMA phase: cached kcs first (no global loads), then streamed ----
    f32x4 acc[2][2];
    acc[0][0] = z4; acc[0][1] = z4; acc[1][0] = z4; acc[1][1] = z4;
#pragma unroll
    for (int j = 0; j < NC; ++j) {
      MFMA_STEP(tkc0 + j, BcL[j], BcH[j]);
    }
#pragma unroll 4
    for (int kc = tkc0 + NC; kc < tkcn; ++kc) {
      const int kcw = kc + tkadd;
      uint4 B0 = wp[wbase_u + (size_t)((kcw * 3 + tg) * 2 + 0) * 64 + l];
      uint4 B1 = wp[wbase_u + (size_t)((kcw * 3 + tg) * 2 + 1) * 64 + l];
      half8 b0 = __builtin_bit_cast(half8, B0);
      half8 b1 = __builtin_bit_cast(half8, B1);
      MFMA_STEP(kc, b0, b1);
    }

    // ---- publish fp16 partial tiles (task w) ----
#pragma unroll
    for (int s = 0; s < 2; ++s)
#pragma unroll
      for (int n = 0; n < 2; ++n)
#pragma unroll
        for (int rgp = 0; rgp < 2; ++rgp) {
          u32 v = (u32)f2h(acc[s][n][rgp * 2]) |
                  ((u32)f2h(acc[s][n][rgp * 2 + 1]) << 16);
          glds16[((((w * 2 + s) * 2 + n) * 2 + rgp)) * 64 + l] = v;
        }
    __syncthreads();                         // B2: all partials + xlds reads done

    // ---- gate math (waves 0-3 own subtiles) ----
    if (w < 4) {
      float gv[8][4];
#pragma unroll
      for (int task = 0; task < 8; ++task)
#pragma unroll
        for (int rgp = 0; rgp < 2; ++rgp) {
          u32 v = glds16[((((task * 2 + usub) * 2 + uni) * 2 + rgp)) * 64 + l];
          gv[task][rgp * 2]     = h2f((u16)v);
          gv[task][rgp * 2 + 1] = h2f((u16)(v >> 16));
        }
#pragma unroll
      for (int rg = 0; rg < 4; ++rg) {
        float R   = gv[0][rg] + gv[1][rg] + gv[2][rg] + br;
        float Z   = gv[3][rg] + gv[4][rg] + gv[5][rg] + bz;
        float XNv = gv[6][rg] + bxn;
        float HNv = gv[7][rg] + bhn;
        float r_ = 1.f / (1.f + __expf(-R));
        float z_ = 1.f / (1.f + __expf(-Z));
        float pre = XNv + r_ * HNv;
        float e2 = __expf(2.f * pre);
        float n_ = 1.f - 2.f / (e2 + 1.f);
        float hn_ = (1.f - z_) * n_ + z_ * hold[rg];
        hold[rg] = hn_;
        hbf[(usub * 16 + l4 * 4 + rg) * 40 + uni * 16 + l15] = f2h(hn_);
      }
    }
    __syncthreads();                         // B3: hbf ready

    // ---- write h(t+1) chunk kc=jt (waves 0,1) ----
    if (w < 2) {
      const int row = w * 16 + l15;
      const uint4 hv = *(const uint4*)&hbf[(size_t)row * 40 + l4 * 8];
      u64 lo = ((u64)hv.y << 32) | (u64)hv.x;
      u64 hi = ((u64)hv.w << 32) | (u64)hv.z;
      u64* dst = hbuf + (size_t)((par ^ 1) * MT + m) * HB_U64_PER
                      + ((size_t)(jt * 2 + w) * 64 + l) * 2;
      __hip_atomic_store(dst, lo, __ATOMIC_RELAXED, __HIP_MEMORY_SCOPE_AGENT);
      __hip_atomic_store(dst + 1, hi, __ATOMIC_RELAXED, __HIP_MEMORY_SCOPE_AGENT);
    }
    asm volatile("s_waitcnt vmcnt(0)" ::: "memory");  // h-stores ACKed at LLC
    __syncthreads();                         // B4
    if (tid == 0)
      __hip_atomic_store(fl + jt, (u32)(t + 1), __ATOMIC_RELAXED, __HIP_MEMORY_SCOPE_AGENT);

    // ---- prefetch x(t+1): flies during next wait + h-DMA ----
    if (t + 1 < NT) ISSUE_X(t + 1);
  }
}

// ---------------- logits pass: out[b, s, :] = hs[s] @ Wout^T + bout ----------------
__global__ __launch_bounds__(256, 1)
void logits_pass(const u16* __restrict__ harch, const u64* __restrict__ hbuf,
                 const u16* __restrict__ wopack, const float* __restrict__ bout,
                 float* __restrict__ out) {
  __shared__ uint4 hlds[HKC * 2 * 64];       // 64KB h tile
  __shared__ f32x4 redv[4 * 3 * 64];         // 3KB exchange
  const int bid = blockIdx.x;
  const int m = bid >> 9;                    // 0..7
  const int s = bid & 511;                   // 0..511
  const int tid = threadIdx.x;
  const int w = tid >> 6, l = tid & 63;
  const int l15 = l & 15, l4 = l >> 4;
  const int usub = w >> 1, uni = w & 1;
  const uint4* wo = (const uint4*)wopack;
  const f32x4 z4 = {0.f, 0.f, 0.f, 0.f};

  // stage h tile: slot s<511 from archive, s==511 from hbuf parity 0
  const char* gb = (s < 511)
      ? (const char*)(harch + (size_t)(m * NT + s) * XSLOT_U16)
      : (const char*)(hbuf + (size_t)(0 * MT + m) * HB_U64_PER);
#pragma unroll
  for (int k = 0; k < 16; ++k)
    gll16c(gb + ((size_t)(k * 256 + tid)) * 16, (void*)(hlds + (k * 256 + w * 64)));
  asm volatile("s_waitcnt vmcnt(0)" ::: "memory");
  __syncthreads();

  f32x4 aL[2][2];
  aL[0][0] = z4; aL[0][1] = z4; aL[1][0] = z4; aL[1][1] = z4;
#pragma unroll
  for (int c_ = 0; c_ < 8; ++c_) {
    const int kc_ = w * 8 + c_;
    uint4 A0 = hlds[(kc_ * 2 + 0) * 64 + l];
    uint4 A1 = hlds[(kc_ * 2 + 1) * 64 + l];
    uint4 O0 = wo[(size_t)(kc_ * 2 + 0) * 64 + l];
    uint4 O1 = wo[(size_t)(kc_ * 2 + 1) * 64 + l];
    half8 a0 = __builtin_bit_cast(half8, A0);
    half8 a1 = __builtin_bit_cast(half8, A1);
    half8 o0 = __builtin_bit_cast(half8, O0);
    half8 o1 = __builtin_bit_cast(half8, O1);
    aL[0][0] = MFMA16(a0, o0, aL[0][0]);
    aL[0][1] = MFMA16(a0, o1, aL[0][1]);
    aL[1][0] = MFMA16(a1, o0, aL[1][0]);
    aL[1][1] = MFMA16(a1, o1, aL[1][1]);
  }
  f32x4 sL;
#pragma unroll
  for (int o = 0; o < 4; ++o) {
    if (o == w) sL = aL[usub][uni];
    else {
      const int slot = (w > o) ? (w - 1) : w;
      redv[(o * 3 + slot) * 64 + l] = aL[o >> 1][o & 1];
    }
  }
  __syncthreads();
#pragma unroll
  for (int slot = 0; slot < 3; ++slot)
    sL += redv[(w * 3 + slot) * 64 + l];
  const int col = uni * 16 + l15;
  if (col < NL) {
#pragma unroll
    for (int rg = 0; rg < 4; ++rg) {
      const int row = usub * 16 + l4 * 4 + rg;
      const size_t b_ = (size_t)m * 32 + row;
      out[(b_ * NT + s) * NL + col] = sL[rg] + bout[col];
    }
  }
}

extern "C" void kernel_launch(void* const* d_in, const int* in_sizes, int n_in,
                              void* d_out, int out_size, void* d_ws, size_t ws_size,
                              hipStream_t stream) {
  (void)in_sizes; (void)n_in; (void)out_size;
  const float* seg   = (const float*)d_in[0];
  const int*   labels= (const int*)d_in[1];
  const float* emb   = (const float*)d_in[2];
  const float* Wih   = (const float*)d_in[3];
  const float* Whh   = (const float*)d_in[4];
  const float* bih   = (const float*)d_in[5];
  const float* bhh   = (const float*)d_in[6];
  const float* Wout  = (const float*)d_in[7];
  const float* bout  = (const float*)d_in[8];
  float* out = (float*)d_out;
  char* ws = (char*)d_ws;
  if (ws_size < WS_TOTAL) return;

  zero_ws<<<129, 256, 0, stream>>>((uint4*)(ws + WS_CNT));
  pack_w<<<3280, 256, 0, stream>>>(Wih, Whh, Wout,
                                   (u16*)(ws + WS_WPACK), (u16*)(ws + WS_WOPACK));
  pack_x<<<4096, 256, 0, stream>>>(seg, labels, emb, (u16*)(ws + WS_XPACK));
  gru_persist<<<NBLK, THREADS, 0, stream>>>(
      (u16*)(ws + WS_XPACK), (const u16*)(ws + WS_WPACK), bih, bhh,
      (u64*)(ws + WS_HBUF), (u32*)(ws + WS_CNT));
  logits_pass<<<MT * NT, 256, 0, stream>>>(
      (const u16*)(ws + WS_XPACK), (const u64*)(ws + WS_HBUF),
      (const u16*)(ws + WS_WOPACK), bout, out);
}

// Round 20
// 3872.523 us; speedup vs baseline: 1.9266x; 1.0374x over previous
//
#include <hip/hip_runtime.h>
#include <hip/hip_fp16.h>

typedef unsigned short u16;
typedef unsigned int u32;
typedef unsigned long long u64;

#define NT 512      // time steps
#define NB 256      // batch
#define NH 1024     // hidden
#define NE 128      // emb dim
#define NHE 1152    // H+E
#define NL 17       // labels
#define MT 8        // batch groups (32 rows each)
#define JTILES 32   // hidden-col tiles (32 cols each)
#define XKC 36      // K-chunks (32 wide) for x part
#define HKC 32      // K-chunks for h part
#define KCT 68      // XKC + HKC
#define NBLK 256    // MT * JTILES
#define THREADS 512 // 8 waves, k-split across gates
#define NC 18       // B kc-units register-cached per wave (loop-invariant)

typedef __attribute__((ext_vector_type(8))) _Float16 half8;
typedef __attribute__((ext_vector_type(4))) float f32x4;

// ---- workspace layout (bytes) ----
#define WS_CNT     0ull
#define WS_HBUF    4096ull
#define WS_WPACK   1052672ull                // 32*68*6*1024     = 13,369,344
#define WS_WOPACK  14422016ull               // 32*2*1024        = 65,536
#define WS_XPACK   14487552ull               // 8*512*36*2*64*16 = 301,989,888
#define WS_TOTAL   316477440ull

#define HB_U64_PER (HKC * 2 * 64 * 2)        // 8192 u64 per (par,m)
#define XSLOT_U16  (XKC * 2 * 64 * 8)        // 36864 u16 per (m,t) x slot (73728B)

__device__ __forceinline__ u16 f2h(float f) {
  __half h = __float2half(f);
  return __builtin_bit_cast(u16, h);
}
__device__ __forceinline__ float h2f(u16 u) {
  return __half2float(__builtin_bit_cast(__half, u));
}
__device__ __forceinline__ uint4 pack8h(const u16* o) {
  uint4 v;
  v.x = (u32)o[0] | ((u32)o[1] << 16);
  v.y = (u32)o[2] | ((u32)o[3] << 16);
  v.z = (u32)o[4] | ((u32)o[5] << 16);
  v.w = (u32)o[6] | ((u32)o[7] << 16);
  return v;
}

// global->LDS DMA, 16B/lane. aux=17 (sc0|sc1): coherent LLC read (h handoff).
__device__ __forceinline__ void gll16u(const void* g, void* l) {
  __builtin_amdgcn_global_load_lds((const __attribute__((address_space(1))) u32*)g,
                                   (__attribute__((address_space(3))) u32*)l, 16, 0, 17);
}
// aux=0: normal cached read (x stream; shared via L2/L3).
__device__ __forceinline__ void gll16c(const void* g, void* l) {
  __builtin_amdgcn_global_load_lds((const __attribute__((address_space(1))) u32*)g,
                                   (__attribute__((address_space(3))) u32*)l, 16, 0, 0);
}

// ---------------- zero flags + h parity-0 ----------------
__global__ void zero_ws(uint4* p) {
  int idx = blockIdx.x * 256 + threadIdx.x;
  if (idx < 33024) {
    uint4 z; z.x = 0; z.y = 0; z.z = 0; z.w = 0;
    p[idx] = z;
  }
}

// ---------------- pack weights into B-fragment order ----------------
__global__ void pack_w(const float* __restrict__ Wih, const float* __restrict__ Whh,
                       const float* __restrict__ Wout, u16* __restrict__ wpack,
                       u16* __restrict__ wopack) {
  int idx = blockIdx.x * 256 + threadIdx.x;
  const int WUNITS = JTILES * KCT * 3 * 2 * 64;   // 835584
  if (idx < WUNITS) {
    int l = idx & 63;
    int r = idx >> 6;
    int ni = r & 1; r >>= 1;
    int g = r % 3;  r /= 3;
    int kc = r % KCT; r /= KCT;
    int jt = r;
    int row = g * NH + jt * 32 + ni * 16 + (l & 15);
    int kk = (l >> 4) * 8;
    const float* src = (kc < XKC) ? (Wih + (size_t)row * NHE + kc * 32 + kk)
                                  : (Whh + (size_t)row * NH + (kc - XKC) * 32 + kk);
    u16 o[8];
#pragma unroll
    for (int e = 0; e < 8; ++e) o[e] = f2h(src[e]);
    ((uint4*)wpack)[idx] = pack8h(o);
  } else if (idx < WUNITS + HKC * 2 * 64) {
    int j = idx - WUNITS;
    int l = j & 63; j >>= 6;
    int ni = j & 1; int kc = j >> 1;
    int col = (l & 15) + 16 * ni;
    int kk = kc * 32 + (l >> 4) * 8;
    u16 o[8];
#pragma unroll
    for (int e = 0; e < 8; ++e)
      o[e] = (col < NL) ? f2h(Wout[(size_t)col * NH + kk + e]) : (u16)0;
    ((uint4*)wopack)[idx - WUNITS] = pack8h(o);
  }
}

// ---------------- pack x = [seg | emb(prev)] into A-fragment order ----------------
__global__ void pack_x(const float* __restrict__ seg, const int* __restrict__ labels,
                       const float* __restrict__ emb, u16* __restrict__ xpack) {
  __shared__ float ls[32][65];
  __shared__ int lbl[32];
  const int bid = blockIdx.x;
  const int t = bid & (NT - 1);
  const int m = bid >> 9;                    // 0..7
  const int tid = threadIdx.x;
  u16* outb = xpack + (size_t)(m * NT + t) * XSLOT_U16;
  const int r = tid >> 3, qq = tid & 7;      // 32 rows x 8 col-chunks
  const int l = tid & 63;

  for (int kc2 = 0; kc2 < 16; ++kc2) {       // stage 64 cols of seg at a time
    const float* s = seg + ((size_t)(m * 32 + r) * NT + t) * NH + kc2 * 64 + qq * 8;
    float4 a = ((const float4*)s)[0];
    float4 b2 = ((const float4*)s)[1];
    ls[r][qq * 8 + 0] = a.x;  ls[r][qq * 8 + 1] = a.y;
    ls[r][qq * 8 + 2] = a.z;  ls[r][qq * 8 + 3] = a.w;
    ls[r][qq * 8 + 4] = b2.x; ls[r][qq * 8 + 5] = b2.y;
    ls[r][qq * 8 + 6] = b2.z; ls[r][qq * 8 + 7] = b2.w;
    __syncthreads();
    const int sub2 = tid >> 6;               // 0..3 -> (kc half, sub)
    const int kc = kc2 * 2 + (sub2 >> 1);
    const int sub = sub2 & 1;
    const int row = sub * 16 + (l & 15);
    const int c0 = (sub2 >> 1) * 32 + (l >> 4) * 8;
    u16 o[8];
#pragma unroll
    for (int e = 0; e < 8; ++e) o[e] = f2h(ls[row][c0 + e]);
    ((uint4*)outb)[(kc * 2 + sub) * 64 + l] = pack8h(o);
    __syncthreads();
  }
  if (tid < 32)
    lbl[tid] = (t == 0) ? NL : labels[(size_t)(m * 32 + tid) * NT + (t - 1)];
  __syncthreads();
#pragma unroll
  for (int k = 0; k < 2; ++k) {
    int u = tid + k * 256;                   // 512 units: kc 32..35, sub, l
    int kc = 32 + (u >> 7);
    int sub = (u >> 6) & 1;
    int ll = u & 63;
    int row = sub * 16 + (ll & 15);
    int c = (kc - 32) * 32 + (ll >> 4) * 8;
    const float* s = emb + (size_t)lbl[row] * NE + c;
    float4 a = ((const float4*)s)[0];
    float4 b2 = ((const float4*)s)[1];
    u16 o[8];
    o[0] = f2h(a.x); o[1] = f2h(a.y); o[2] = f2h(a.z); o[3] = f2h(a.w);
    o[4] = f2h(b2.x); o[5] = f2h(b2.y); o[6] = f2h(b2.z); o[7] = f2h(b2.w);
    ((uint4*)outb)[(kc * 2 + sub) * 64 + ll] = pack8h(o);
  }
}

// ---------------- persistent GRU kernel ----------------
#define MFMA16(a, b, c) __builtin_amdgcn_mfma_f32_16x16x32_f16((a), (b), (c), 0, 0, 0)

// all-lane wait with throttled polling
#define WAIT_FLAGS(tgt) do { \
  while (true) { \
    u32 v_ = __hip_atomic_load(fl + (l & 31), __ATOMIC_RELAXED, __HIP_MEMORY_SCOPE_AGENT); \
    if (__all((int)v_ >= (tgt))) break; \
    __builtin_amdgcn_s_sleep(2); \
  } \
} while (0)

// issue x(tt) DMA into xlds (not drained here): 4608 units / 512 threads = 9
#define ISSUE_X(tt) do { \
  const char* xgb_ = (const char*)xpack + (size_t)(m * NT + (tt)) * (XSLOT_U16 * 2); \
  _Pragma("unroll") \
  for (int k_ = 0; k_ < 9; ++k_) \
    gll16c(xgb_ + ((size_t)(k_ * 512 + tid)) * 16, (void*)(xlds + (k_ * 512 + w * 64))); \
} while (0)

// one MFMA kc-step given A-src index and B fragments
#define MFMA_STEP(kcA, B0h, B1h) do { \
  uint4 A0 = asrc[((kcA) * 2 + 0) * 64 + l]; \
  uint4 A1 = asrc[((kcA) * 2 + 1) * 64 + l]; \
  half8 a0 = __builtin_bit_cast(half8, A0); \
  half8 a1 = __builtin_bit_cast(half8, A1); \
  acc[0][0] = MFMA16(a0, (B0h), acc[0][0]); \
  acc[0][1] = MFMA16(a0, (B1h), acc[0][1]); \
  acc[1][0] = MFMA16(a1, (B0h), acc[1][0]); \
  acc[1][1] = MFMA16(a1, (B1h), acc[1][1]); \
} while (0)

__global__ __launch_bounds__(THREADS, 1)
void gru_persist(u16* xpack, const u16* __restrict__ wpack,
                 const float* __restrict__ bih, const float* __restrict__ bhh,
                 u64* __restrict__ hbuf, u32* __restrict__ counters) {
  __shared__ uint4 hlds[HKC * 2 * 64];           // 64KB h(t) tile (frag-linear)
  __shared__ uint4 xlds[XKC * 2 * 64];           // 72KB x(t) tile (frag-linear)
  __shared__ u32 glds16[8 * 2 * 2 * 2 * 64];     // 16KB fp16 gate partials (8 tasks)
  __shared__ u16 hbf[32 * 40];                   // 2.5KB fp16 bounce

  const int bid = blockIdx.x;
  const int xcd = bid & 7;
  const int q = bid >> 3;
  const int m = q & 7;
  const int jslot = q >> 3;
  const int jt = jslot * 8 + xcd;            // weights L2-resident per XCD
  const int tid = threadIdx.x;
  const int w = tid >> 6, l = tid & 63;
  const int l15 = l & 15, l4 = l >> 4;
  const int usub = (w >> 1) & 1, uni = w & 1; // update subtile for waves 0-3

  const uint4* wp = (const uint4*)wpack;
  u32* fl = counters + m * 64;               // 32 flags per group
  const size_t wbase_u = (size_t)jt * (KCT * 6 * 64);

  const int ocol = jt * 32 + uni * 16 + l15;
  const float br = bih[ocol] + bhh[ocol];
  const float bz = bih[NH + ocol] + bhh[NH + ocol];
  const float bxn = bih[2 * NH + ocol];
  const float bhn = bhh[2 * NH + ocol];
  float hold[4] = {0.f, 0.f, 0.f, 0.f};
  const f32x4 z4 = {0.f, 0.f, 0.f, 0.f};

  // wave task table: w0,w1,w2 -> R(x1,x2,h); w3,w4,w5 -> Z(x1,x2,h);
  // w6 -> XN(x); w7 -> HN(h). max 36 kc per wave.
  int tg, tkc0, tkcn; bool tIsX;
  if (w == 6)      { tg = 2; tIsX = true;  tkc0 = 0;  tkcn = 36; }
  else if (w == 7) { tg = 2; tIsX = false; tkc0 = 0;  tkcn = 32; }
  else {
    tg = (w < 3) ? 0 : 1;
    const int r_ = (w < 3) ? w : (w - 3);
    tIsX = (r_ < 2);
    tkc0 = (r_ == 1) ? 18 : 0;
    tkcn = tIsX ? ((r_ == 0) ? 18 : 36) : 32;
  }
  const int tkadd = tIsX ? 0 : XKC;          // kc -> wpack kc index offset
  const uint4* asrc = tIsX ? xlds : hlds;

  // archive-store thread mapping (2KB chunk jt of hlds -> dead xpack slot)
  const int a_sub = (tid >> 7) & 1, a_half = (tid >> 6) & 1, a_l = tid & 63;
  const size_t a_off = ((size_t)(jt * 2 + a_sub) * 64 + a_l) * 2 + a_half;

  // ---- register-cache the first NC kc of this wave's B slice (loop-invariant)
  // statically indexed; all tasks have tkcn-tkc0 >= 18 == NC
  half8 BcL[NC], BcH[NC];
#pragma unroll
  for (int j = 0; j < NC; ++j) {
    const int kcw = tkc0 + j + tkadd;
    BcL[j] = __builtin_bit_cast(half8, wp[wbase_u + (size_t)((kcw * 3 + tg) * 2 + 0) * 64 + l]);
    BcH[j] = __builtin_bit_cast(half8, wp[wbase_u + (size_t)((kcw * 3 + tg) * 2 + 1) * 64 + l]);
  }

  // ---- prologue: issue x(0) ----
  ISSUE_X(0);

  for (int t = 0; t < NT; ++t) {
    const int par = t & 1;

    // ---- wait for group's h(t) (x(t) DMA already in flight) ----
    WAIT_FLAGS(t);

    // ---- DMA h(t) (coherent LLC); drain x+h together ----
    {
      const char* gb = (const char*)hbuf + ((size_t)(par * MT + m) * HB_U64_PER) * 8;
#pragma unroll
      for (int k = 0; k < 8; ++k)
        gll16u(gb + ((size_t)(k * 512 + tid)) * 16, (void*)(hlds + (k * 512 + w * 64)));
      asm volatile("s_waitcnt vmcnt(0)" ::: "memory");
      __syncthreads();                       // B1: hlds + xlds ready
    }

    // ---- archive h(t) chunk jt into dead xpack slot (m, t-1) ----
    if (t > 0 && tid < 256) {
      const u64 v = ((const u64*)hlds)[a_off];
      u64* dst = (u64*)(xpack + (size_t)(m * NT + (t - 1)) * XSLOT_U16);
      dst[a_off] = v;
    }

    // ---- MFMA phase: cached kcs first (no global loads), then streamed ----
    f32x4 acc[2][2];
    acc[0][0] = z4; acc[0][1] = z4; acc[1][0] = z4; acc[1][1] = z4;
#pragma unroll
    for (int j = 0; j < NC; ++j) {
      MFMA_STEP(tkc0 + j, BcL[j], BcH[j]);
    }
#pragma unroll 4
    for (int kc = tkc0 + NC; kc < tkcn; ++kc) {
      const int kcw = kc + tkadd;
      uint4 B0 = wp[wbase_u + (size_t)((kcw * 3 + tg) * 2 + 0) * 64 + l];
      uint4 B1 = wp[wbase_u + (size_t)((kcw * 3 + tg) * 2 + 1) * 64 + l];
      half8 b0 = __builtin_bit_cast(half8, B0);
      half8 b1 = __builtin_bit_cast(half8, B1);
      MFMA_STEP(kc, b0, b1);
    }

    // ---- publish fp16 partial tiles (task w) ----
#pragma unroll
    for (int s = 0; s < 2; ++s)
#pragma unroll
      for (int n = 0; n < 2; ++n)
#pragma unroll
        for (int rgp = 0; rgp < 2; ++rgp) {
          u32 v = (u32)f2h(acc[s][n][rgp * 2]) |
                  ((u32)f2h(acc[s][n][rgp * 2 + 1]) << 16);
          glds16[((((w * 2 + s) * 2 + n) * 2 + rgp)) * 64 + l] = v;
        }
    __syncthreads();                         // B2: all partials + xlds reads done

    // ---- gate math (waves 0-3 own subtiles) ----
    if (w < 4) {
      float gv[8][4];
#pragma unroll
      for (int task = 0; task < 8; ++task)
#pragma unroll
        for (int rgp = 0; rgp < 2; ++rgp) {
          u32 v = glds16[((((task * 2 + usub) * 2 + uni) * 2 + rgp)) * 64 + l];
          gv[task][rgp * 2]     = h2f((u16)v);
          gv[task][rgp * 2 + 1] = h2f((u16)(v >> 16));
        }
#pragma unroll
      for (int rg = 0; rg < 4; ++rg) {
        float R   = gv[0][rg] + gv[1][rg] + gv[2][rg] + br;
        float Z   = gv[3][rg] + gv[4][rg] + gv[5][rg] + bz;
        float XNv = gv[6][rg] + bxn;
        float HNv = gv[7][rg] + bhn;
        float r_ = 1.f / (1.f + __expf(-R));
        float z_ = 1.f / (1.f + __expf(-Z));
        float pre = XNv + r_ * HNv;
        float e2 = __expf(2.f * pre);
        float n_ = 1.f - 2.f / (e2 + 1.f);
        float hn_ = (1.f - z_) * n_ + z_ * hold[rg];
        hold[rg] = hn_;
        hbf[(usub * 16 + l4 * 4 + rg) * 40 + uni * 16 + l15] = f2h(hn_);
      }
    }
    __syncthreads();                         // B3: hbf ready

    // ---- write h(t+1) chunk kc=jt (waves 0,1) ----
    if (w < 2) {
      const int row = w * 16 + l15;
      const uint4 hv = *(const uint4*)&hbf[(size_t)row * 40 + l4 * 8];
      u64 lo = ((u64)hv.y << 32) | (u64)hv.x;
      u64 hi = ((u64)hv.w << 32) | (u64)hv.z;
      u64* dst = hbuf + (size_t)((par ^ 1) * MT + m) * HB_U64_PER
                      + ((size_t)(jt * 2 + w) * 64 + l) * 2;
      __hip_atomic_store(dst, lo, __ATOMIC_RELAXED, __HIP_MEMORY_SCOPE_AGENT);
      __hip_atomic_store(dst + 1, hi, __ATOMIC_RELAXED, __HIP_MEMORY_SCOPE_AGENT);
    }
    asm volatile("s_waitcnt vmcnt(0)" ::: "memory");  // h-stores ACKed at LLC
    __syncthreads();                         // B4
    if (tid == 0)
      __hip_atomic_store(fl + jt, (u32)(t + 1), __ATOMIC_RELAXED, __HIP_MEMORY_SCOPE_AGENT);

    // ---- prefetch x(t+1): flies during next wait + h-DMA ----
    if (t + 1 < NT) ISSUE_X(t + 1);
  }
}

// ---------------- logits pass: out[b, s, :] = hs[s] @ Wout^T + bout ----------------
__global__ __launch_bounds__(256, 1)
void logits_pass(const u16* __restrict__ harch, const u64* __restrict__ hbuf,
                 const u16* __restrict__ wopack, const float* __restrict__ bout,
                 float* __restrict__ out) {
  __shared__ uint4 hlds[HKC * 2 * 64];       // 64KB h tile
  __shared__ f32x4 redv[4 * 3 * 64];         // 3KB exchange
  const int bid = blockIdx.x;
  const int m = bid >> 9;                    // 0..7
  const int s = bid & 511;                   // 0..511
  const int tid = threadIdx.x;
  const int w = tid >> 6, l = tid & 63;
  const int l15 = l & 15, l4 = l >> 4;
  const int usub = w >> 1, uni = w & 1;
  const uint4* wo = (const uint4*)wopack;
  const f32x4 z4 = {0.f, 0.f, 0.f, 0.f};

  // stage h tile: slot s<511 from archive, s==511 from hbuf parity 0
  const char* gb = (s < 511)
      ? (const char*)(harch + (size_t)(m * NT + s) * XSLOT_U16)
      : (const char*)(hbuf + (size_t)(0 * MT + m) * HB_U64_PER);
#pragma unroll
  for (int k = 0; k < 16; ++k)
    gll16c(gb + ((size_t)(k * 256 + tid)) * 16, (void*)(hlds + (k * 256 + w * 64)));
  asm volatile("s_waitcnt vmcnt(0)" ::: "memory");
  __syncthreads();

  f32x4 aL[2][2];
  aL[0][0] = z4; aL[0][1] = z4; aL[1][0] = z4; aL[1][1] = z4;
#pragma unroll
  for (int c_ = 0; c_ < 8; ++c_) {
    const int kc_ = w * 8 + c_;
    uint4 A0 = hlds[(kc_ * 2 + 0) * 64 + l];
    uint4 A1 = hlds[(kc_ * 2 + 1) * 64 + l];
    uint4 O0 = wo[(size_t)(kc_ * 2 + 0) * 64 + l];
    uint4 O1 = wo[(size_t)(kc_ * 2 + 1) * 64 + l];
    half8 a0 = __builtin_bit_cast(half8, A0);
    half8 a1 = __builtin_bit_cast(half8, A1);
    half8 o0 = __builtin_bit_cast(half8, O0);
    half8 o1 = __builtin_bit_cast(half8, O1);
    aL[0][0] = MFMA16(a0, o0, aL[0][0]);
    aL[0][1] = MFMA16(a0, o1, aL[0][1]);
    aL[1][0] = MFMA16(a1, o0, aL[1][0]);
    aL[1][1] = MFMA16(a1, o1, aL[1][1]);
  }
  f32x4 sL;
#pragma unroll
  for (int o = 0; o < 4; ++o) {
    if (o == w) sL = aL[usub][uni];
    else {
      const int slot = (w > o) ? (w - 1) : w;
      redv[(o * 3 + slot) * 64 + l] = aL[o >> 1][o & 1];
    }
  }
  __syncthreads();
#pragma unroll
  for (int slot = 0; slot < 3; ++slot)
    sL += redv[(w * 3 + slot) * 64 + l];
  const int col = uni * 16 + l15;
  if (col < NL) {
#pragma unroll
    for (int rg = 0; rg < 4; ++rg) {
      const int row = usub * 16 + l4 * 4 + rg;
      const size_t b_ = (size_t)m * 32 + row;
      out[(b_ * NT + s) * NL + col] = sL[rg] + bout[col];
    }
  }
}

extern "C" void kernel_launch(void* const* d_in, const int* in_sizes, int n_in,
                              void* d_out, int out_size, void* d_ws, size_t ws_size,
                              hipStream_t stream) {
  (void)in_sizes; (void)n_in; (void)out_size;
  const float* seg   = (const float*)d_in[0];
  const int*   labels= (const int*)d_in[1];
  const float* emb   = (const float*)d_in[2];
  const float* Wih   = (const float*)d_in[3];
  const float* Whh   = (const float*)d_in[4];
  const float* bih   = (const float*)d_in[5];
  const float* bhh   = (const float*)d_in[6];
  const float* Wout  = (const float*)d_in[7];
  const float* bout  = (const float*)d_in[8];
  float* out = (float*)d_out;
  char* ws = (char*)d_ws;
  if (ws_size < WS_TOTAL) return;

  zero_ws<<<129, 256, 0, stream>>>((uint4*)(ws + WS_CNT));
  pack_w<<<3280, 256, 0, stream>>>(Wih, Whh, Wout,
                                   (u16*)(ws + WS_WPACK), (u16*)(ws + WS_WOPACK));
  pack_x<<<4096, 256, 0, stream>>>(seg, labels, emb, (u16*)(ws + WS_XPACK));
  gru_persist<<<NBLK, THREADS, 0, stream>>>(
      (u16*)(ws + WS_XPACK), (const u16*)(ws + WS_WPACK), bih, bhh,
      (u64*)(ws + WS_HBUF), (u32*)(ws + WS_CNT));
  logits_pass<<<MT * NT, 256, 0, stream>>>(
      (const u16*)(ws + WS_XPACK), (const u64*)(ws + WS_HBUF),
      (const u16*)(ws + WS_WOPACK), bout, out);
}

// Round 21
// 3792.818 us; speedup vs baseline: 1.9671x; 1.0210x over previous
//
#include <hip/hip_runtime.h>
#include <hip/hip_fp16.h>

typedef unsigned short u16;
typedef unsigned int u32;
typedef unsigned long long u64;

#define NT 512      // time steps
#define NB 256      // batch
#define NH 1024     // hidden
#define NE 128      // emb dim
#define NHE 1152    // H+E
#define NL 17       // labels
#define MT 8        // batch groups (32 rows each)
#define JTILES 32   // hidden-col tiles (32 cols each)
#define XKC 36      // K-chunks (32 wide) for x part
#define HKC 32      // K-chunks for h part
#define KCT 68      // XKC + HKC
#define NBLK 256    // MT * JTILES
#define THREADS 512 // 8 waves, k-split across gates
#define NC 22       // max B kc-units register-cached per wave (clamped per task)

typedef __attribute__((ext_vector_type(8))) _Float16 half8;
typedef __attribute__((ext_vector_type(4))) float f32x4;

// ---- workspace layout (bytes) ----
#define WS_CNT     0ull
#define WS_HBUF    4096ull
#define WS_WPACK   1052672ull                // 32*68*6*1024     = 13,369,344
#define WS_WOPACK  14422016ull               // 32*2*1024        = 65,536
#define WS_XPACK   14487552ull               // 8*512*36*2*64*16 = 301,989,888
#define WS_TOTAL   316477440ull

#define HB_U64_PER (HKC * 2 * 64 * 2)        // 8192 u64 per (par,m)
#define XSLOT_U16  (XKC * 2 * 64 * 8)        // 36864 u16 per (m,t) x slot (73728B)

__device__ __forceinline__ u16 f2h(float f) {
  __half h = __float2half(f);
  return __builtin_bit_cast(u16, h);
}
__device__ __forceinline__ float h2f(u16 u) {
  return __half2float(__builtin_bit_cast(__half, u));
}
__device__ __forceinline__ uint4 pack8h(const u16* o) {
  uint4 v;
  v.x = (u32)o[0] | ((u32)o[1] << 16);
  v.y = (u32)o[2] | ((u32)o[3] << 16);
  v.z = (u32)o[4] | ((u32)o[5] << 16);
  v.w = (u32)o[6] | ((u32)o[7] << 16);
  return v;
}

// global->LDS DMA, 16B/lane. aux=17 (sc0|sc1): coherent LLC read (h handoff).
__device__ __forceinline__ void gll16u(const void* g, void* l) {
  __builtin_amdgcn_global_load_lds((const __attribute__((address_space(1))) u32*)g,
                                   (__attribute__((address_space(3))) u32*)l, 16, 0, 17);
}
// aux=0: normal cached read (x stream; shared via L2/L3).
__device__ __forceinline__ void gll16c(const void* g, void* l) {
  __builtin_amdgcn_global_load_lds((const __attribute__((address_space(1))) u32*)g,
                                   (__attribute__((address_space(3))) u32*)l, 16, 0, 0);
}

// ---------------- zero flags + h parity-0 ----------------
__global__ void zero_ws(uint4* p) {
  int idx = blockIdx.x * 256 + threadIdx.x;
  if (idx < 33024) {
    uint4 z; z.x = 0; z.y = 0; z.z = 0; z.w = 0;
    p[idx] = z;
  }
}

// ---------------- pack weights into B-fragment order ----------------
__global__ void pack_w(const float* __restrict__ Wih, const float* __restrict__ Whh,
                       const float* __restrict__ Wout, u16* __restrict__ wpack,
                       u16* __restrict__ wopack) {
  int idx = blockIdx.x * 256 + threadIdx.x;
  const int WUNITS = JTILES * KCT * 3 * 2 * 64;   // 835584
  if (idx < WUNITS) {
    int l = idx & 63;
    int r = idx >> 6;
    int ni = r & 1; r >>= 1;
    int g = r % 3;  r /= 3;
    int kc = r % KCT; r /= KCT;
    int jt = r;
    int row = g * NH + jt * 32 + ni * 16 + (l & 15);
    int kk = (l >> 4) * 8;
    const float* src = (kc < XKC) ? (Wih + (size_t)row * NHE + kc * 32 + kk)
                                  : (Whh + (size_t)row * NH + (kc - XKC) * 32 + kk);
    u16 o[8];
#pragma unroll
    for (int e = 0; e < 8; ++e) o[e] = f2h(src[e]);
    ((uint4*)wpack)[idx] = pack8h(o);
  } else if (idx < WUNITS + HKC * 2 * 64) {
    int j = idx - WUNITS;
    int l = j & 63; j >>= 6;
    int ni = j & 1; int kc = j >> 1;
    int col = (l & 15) + 16 * ni;
    int kk = kc * 32 + (l >> 4) * 8;
    u16 o[8];
#pragma unroll
    for (int e = 0; e < 8; ++e)
      o[e] = (col < NL) ? f2h(Wout[(size_t)col * NH + kk + e]) : (u16)0;
    ((uint4*)wopack)[idx - WUNITS] = pack8h(o);
  }
}

// ---------------- pack x = [seg | emb(prev)] into A-fragment order ----------------
__global__ void pack_x(const float* __restrict__ seg, const int* __restrict__ labels,
                       const float* __restrict__ emb, u16* __restrict__ xpack) {
  __shared__ float ls[32][65];
  __shared__ int lbl[32];
  const int bid = blockIdx.x;
  const int t = bid & (NT - 1);
  const int m = bid >> 9;                    // 0..7
  const int tid = threadIdx.x;
  u16* outb = xpack + (size_t)(m * NT + t) * XSLOT_U16;
  const int r = tid >> 3, qq = tid & 7;      // 32 rows x 8 col-chunks
  const int l = tid & 63;

  for (int kc2 = 0; kc2 < 16; ++kc2) {       // stage 64 cols of seg at a time
    const float* s = seg + ((size_t)(m * 32 + r) * NT + t) * NH + kc2 * 64 + qq * 8;
    float4 a = ((const float4*)s)[0];
    float4 b2 = ((const float4*)s)[1];
    ls[r][qq * 8 + 0] = a.x;  ls[r][qq * 8 + 1] = a.y;
    ls[r][qq * 8 + 2] = a.z;  ls[r][qq * 8 + 3] = a.w;
    ls[r][qq * 8 + 4] = b2.x; ls[r][qq * 8 + 5] = b2.y;
    ls[r][qq * 8 + 6] = b2.z; ls[r][qq * 8 + 7] = b2.w;
    __syncthreads();
    const int sub2 = tid >> 6;               // 0..3 -> (kc half, sub)
    const int kc = kc2 * 2 + (sub2 >> 1);
    const int sub = sub2 & 1;
    const int row = sub * 16 + (l & 15);
    const int c0 = (sub2 >> 1) * 32 + (l >> 4) * 8;
    u16 o[8];
#pragma unroll
    for (int e = 0; e < 8; ++e) o[e] = f2h(ls[row][c0 + e]);
    ((uint4*)outb)[(kc * 2 + sub) * 64 + l] = pack8h(o);
    __syncthreads();
  }
  if (tid < 32)
    lbl[tid] = (t == 0) ? NL : labels[(size_t)(m * 32 + tid) * NT + (t - 1)];
  __syncthreads();
#pragma unroll
  for (int k = 0; k < 2; ++k) {
    int u = tid + k * 256;                   // 512 units: kc 32..35, sub, l
    int kc = 32 + (u >> 7);
    int sub = (u >> 6) & 1;
    int ll = u & 63;
    int row = sub * 16 + (ll & 15);
    int c = (kc - 32) * 32 + (ll >> 4) * 8;
    const float* s = emb + (size_t)lbl[row] * NE + c;
    float4 a = ((const float4*)s)[0];
    float4 b2 = ((const float4*)s)[1];
    u16 o[8];
    o[0] = f2h(a.x); o[1] = f2h(a.y); o[2] = f2h(a.z); o[3] = f2h(a.w);
    o[4] = f2h(b2.x); o[5] = f2h(b2.y); o[6] = f2h(b2.z); o[7] = f2h(b2.w);
    ((uint4*)outb)[(kc * 2 + sub) * 64 + ll] = pack8h(o);
  }
}

// ---------------- persistent GRU kernel ----------------
#define MFMA16(a, b, c) __builtin_amdgcn_mfma_f32_16x16x32_f16((a), (b), (c), 0, 0, 0)

// all-lane wait with throttled polling
#define WAIT_FLAGS(tgt) do { \
  while (true) { \
    u32 v_ = __hip_atomic_load(fl + (l & 31), __ATOMIC_RELAXED, __HIP_MEMORY_SCOPE_AGENT); \
    if (__all((int)v_ >= (tgt))) break; \
    __builtin_amdgcn_s_sleep(2); \
  } \
} while (0)

// issue x(tt) DMA into xlds (not drained here): 4608 units / 512 threads = 9
#define ISSUE_X(tt) do { \
  const char* xgb_ = (const char*)xpack + (size_t)(m * NT + (tt)) * (XSLOT_U16 * 2); \
  _Pragma("unroll") \
  for (int k_ = 0; k_ < 9; ++k_) \
    gll16c(xgb_ + ((size_t)(k_ * 512 + tid)) * 16, (void*)(xlds + (k_ * 512 + w * 64))); \
} while (0)

// one MFMA kc-step given A-src index and B fragments
#define MFMA_STEP(kcA, B0h, B1h) do { \
  uint4 A0 = asrc[((kcA) * 2 + 0) * 64 + l]; \
  uint4 A1 = asrc[((kcA) * 2 + 1) * 64 + l]; \
  half8 a0 = __builtin_bit_cast(half8, A0); \
  half8 a1 = __builtin_bit_cast(half8, A1); \
  acc[0][0] = MFMA16(a0, (B0h), acc[0][0]); \
  acc[0][1] = MFMA16(a0, (B1h), acc[0][1]); \
  acc[1][0] = MFMA16(a1, (B0h), acc[1][0]); \
  acc[1][1] = MFMA16(a1, (B1h), acc[1][1]); \
} while (0)

__global__ __launch_bounds__(THREADS, 1)
void gru_persist(u16* xpack, const u16* __restrict__ wpack,
                 const float* __restrict__ bih, const float* __restrict__ bhh,
                 u64* __restrict__ hbuf, u32* __restrict__ counters) {
  __shared__ uint4 hlds[HKC * 2 * 64];           // 64KB h(t) tile (frag-linear)
  __shared__ uint4 xlds[XKC * 2 * 64];           // 72KB x(t) tile (frag-linear)
  __shared__ u32 glds16[8 * 2 * 2 * 2 * 64];     // 16KB fp16 gate partials (8 tasks)
  __shared__ u16 hbf[32 * 40];                   // 2.5KB fp16 bounce

  const int bid = blockIdx.x;
  const int xcd = bid & 7;
  const int q = bid >> 3;
  const int m = q & 7;
  const int jslot = q >> 3;
  const int jt = jslot * 8 + xcd;            // weights L2-resident per XCD
  const int tid = threadIdx.x;
  const int w = tid >> 6, l = tid & 63;
  const int l15 = l & 15, l4 = l >> 4;
  const int usub = (w >> 1) & 1, uni = w & 1; // update subtile for waves 0-3

  const uint4* wp = (const uint4*)wpack;
  u32* fl = counters + m * 64;               // 32 flags per group
  const size_t wbase_u = (size_t)jt * (KCT * 6 * 64);

  const int ocol = jt * 32 + uni * 16 + l15;
  const float br = bih[ocol] + bhh[ocol];
  const float bz = bih[NH + ocol] + bhh[NH + ocol];
  const float bxn = bih[2 * NH + ocol];
  const float bhn = bhh[2 * NH + ocol];
  float hold[4] = {0.f, 0.f, 0.f, 0.f};
  const f32x4 z4 = {0.f, 0.f, 0.f, 0.f};

  // wave task table: w0,w1,w2 -> R(x1,x2,h); w3,w4,w5 -> Z(x1,x2,h);
  // w6 -> XN(x); w7 -> HN(h). max 36 kc per wave.
  int tg, tkc0, tkcn; bool tIsX;
  if (w == 6)      { tg = 2; tIsX = true;  tkc0 = 0;  tkcn = 36; }
  else if (w == 7) { tg = 2; tIsX = false; tkc0 = 0;  tkcn = 32; }
  else {
    tg = (w < 3) ? 0 : 1;
    const int r_ = (w < 3) ? w : (w - 3);
    tIsX = (r_ < 2);
    tkc0 = (r_ == 1) ? 18 : 0;
    tkcn = tIsX ? ((r_ == 0) ? 18 : 36) : 32;
  }
  const int tkadd = tIsX ? 0 : XKC;          // kc -> wpack kc index offset
  const uint4* asrc = tIsX ? xlds : hlds;
  const int ncw = (tkcn - tkc0 < NC) ? (tkcn - tkc0) : NC;  // cached count

  // archive-store thread mapping (2KB chunk jt of hlds -> dead xpack slot)
  const int a_sub = (tid >> 7) & 1, a_half = (tid >> 6) & 1, a_l = tid & 63;
  const size_t a_off = ((size_t)(jt * 2 + a_sub) * 64 + a_l) * 2 + a_half;

  // ---- register-cache the first ncw kc of this wave's B slice (loop-invariant)
  // statically indexed fill (j<ncw guard, unrolled); unused tail regs are dead
  half8 BcL[NC], BcH[NC];
#pragma unroll
  for (int j = 0; j < NC; ++j) {
    const int jj = (j < ncw) ? j : (ncw - 1);   // clamp: redundant load, no OOB
    const int kcw = tkc0 + jj + tkadd;
    BcL[j] = __builtin_bit_cast(half8, wp[wbase_u + (size_t)((kcw * 3 + tg) * 2 + 0) * 64 + l]);
    BcH[j] = __builtin_bit_cast(half8, wp[wbase_u + (size_t)((kcw * 3 + tg) * 2 + 1) * 64 + l]);
  }

  // ---- prologue: issue x(0) ----
  ISSUE_X(0);

  for (int t = 0; t < NT; ++t) {
    const int par = t & 1;

    // ---- wait for group's h(t) (x(t) DMA already in flight) ----
    WAIT_FLAGS(t);

    // ---- DMA h(t) (coherent LLC); drain x+h together ----
    {
      const char* gb = (const char*)hbuf + ((size_t)(par * MT + m) * HB_U64_PER) * 8;
#pragma unroll
      for (int k = 0; k < 8; ++k)
        gll16u(gb + ((size_t)(k * 512 + tid)) * 16, (void*)(hlds + (k * 512 + w * 64)));
      asm volatile("s_waitcnt vmcnt(0)" ::: "memory");
      __syncthreads();                       // B1: hlds + xlds ready
    }

    // ---- archive h(t) chunk jt into dead xpack slot (m, t-1) ----
    if (t > 0 && tid < 256) {
      const u64 v = ((const u64*)hlds)[a_off];
      u64* dst = (u64*)(xpack + (size_t)(m * NT + (t - 1)) * XSLOT_U16);
      dst[a_off] = v;
    }

    // ---- MFMA phase: cached kcs first (no global loads), then streamed ----
    f32x4 acc[2][2];
    acc[0][0] = z4; acc[0][1] = z4; acc[1][0] = z4; acc[1][1] = z4;
#pragma unroll
    for (int j = 0; j < NC; ++j) {
      if (j < ncw) MFMA_STEP(tkc0 + j, BcL[j], BcH[j]);
    }
#pragma unroll 4
    for (int kc = tkc0 + ncw; kc < tkcn; ++kc) {
      const int kcw = kc + tkadd;
      uint4 B0 = wp[wbase_u + (size_t)((kcw * 3 + tg) * 2 + 0) * 64 + l];
      uint4 B1 = wp[wbase_u + (size_t)((kcw * 3 + tg) * 2 + 1) * 64 + l];
      half8 b0 = __builtin_bit_cast(half8, B0);
      half8 b1 = __builtin_bit_cast(half8, B1);
      MFMA_STEP(kc, b0, b1);
    }

    // ---- publish fp16 partial tiles (task w) ----
#pragma unroll
    for (int s = 0; s < 2; ++s)
#pragma unroll
      for (int n = 0; n < 2; ++n)
#pragma unroll
        for (int rgp = 0; rgp < 2; ++rgp) {
          u32 v = (u32)f2h(acc[s][n][rgp * 2]) |
                  ((u32)f2h(acc[s][n][rgp * 2 + 1]) << 16);
          glds16[((((w * 2 + s) * 2 + n) * 2 + rgp)) * 64 + l] = v;
        }
    __syncthreads();                         // B2: all partials + xlds reads done

    // ---- gate math (waves 0-3 own subtiles) ----
    if (w < 4) {
      float gv[8][4];
#pragma unroll
      for (int task = 0; task < 8; ++task)
#pragma unroll
        for (int rgp = 0; rgp < 2; ++rgp) {
          u32 v = glds16[((((task * 2 + usub) * 2 + uni) * 2 + rgp)) * 64 + l];
          gv[task][rgp * 2]     = h2f((u16)v);
          gv[task][rgp * 2 + 1] = h2f((u16)(v >> 16));
        }
#pragma unroll
      for (int rg = 0; rg < 4; ++rg) {
        float R   = gv[0][rg] + gv[1][rg] + gv[2][rg] + br;
        float Z   = gv[3][rg] + gv[4][rg] + gv[5][rg] + bz;
        float XNv = gv[6][rg] + bxn;
        float HNv = gv[7][rg] + bhn;
        float r_ = 1.f / (1.f + __expf(-R));
        float z_ = 1.f / (1.f + __expf(-Z));
        float pre = XNv + r_ * HNv;
        float e2 = __expf(2.f * pre);
        float n_ = 1.f - 2.f / (e2 + 1.f);
        float hn_ = (1.f - z_) * n_ + z_ * hold[rg];
        hold[rg] = hn_;
        hbf[(usub * 16 + l4 * 4 + rg) * 40 + uni * 16 + l15] = f2h(hn_);
      }
    }
    __syncthreads();                         // B3: hbf ready

    // ---- write h(t+1) chunk kc=jt (waves 0,1) ----
    if (w < 2) {
      const int row = w * 16 + l15;
      const uint4 hv = *(const uint4*)&hbf[(size_t)row * 40 + l4 * 8];
      u64 lo = ((u64)hv.y << 32) | (u64)hv.x;
      u64 hi = ((u64)hv.w << 32) | (u64)hv.z;
      u64* dst = hbuf + (size_t)((par ^ 1) * MT + m) * HB_U64_PER
                      + ((size_t)(jt * 2 + w) * 64 + l) * 2;
      __hip_atomic_store(dst, lo, __ATOMIC_RELAXED, __HIP_MEMORY_SCOPE_AGENT);
      __hip_atomic_store(dst + 1, hi, __ATOMIC_RELAXED, __HIP_MEMORY_SCOPE_AGENT);
    }
    asm volatile("s_waitcnt vmcnt(0)" ::: "memory");  // h-stores ACKed at LLC
    __syncthreads();                         // B4
    if (tid == 0)
      __hip_atomic_store(fl + jt, (u32)(t + 1), __ATOMIC_RELAXED, __HIP_MEMORY_SCOPE_AGENT);

    // ---- prefetch x(t+1): flies during next wait + h-DMA ----
    if (t + 1 < NT) ISSUE_X(t + 1);
  }
}

// ---------------- logits pass: out[b, s, :] = hs[s] @ Wout^T + bout ----------------
__global__ __launch_bounds__(256, 1)
void logits_pass(const u16* __restrict__ harch, const u64* __restrict__ hbuf,
                 const u16* __restrict__ wopack, const float* __restrict__ bout,
                 float* __restrict__ out) {
  __shared__ uint4 hlds[HKC * 2 * 64];       // 64KB h tile
  __shared__ f32x4 redv[4 * 3 * 64];         // 3KB exchange
  const int bid = blockIdx.x;
  const int m = bid >> 9;                    // 0..7
  const int s = bid & 511;                   // 0..511
  const int tid = threadIdx.x;
  const int w = tid >> 6, l = tid & 63;
  const int l15 = l & 15, l4 = l >> 4;
  const int usub = w >> 1, uni = w & 1;
  const uint4* wo = (const uint4*)wopack;
  const f32x4 z4 = {0.f, 0.f, 0.f, 0.f};

  // stage h tile: slot s<511 from archive, s==511 from hbuf parity 0
  const char* gb = (s < 511)
      ? (const char*)(harch + (size_t)(m * NT + s) * XSLOT_U16)
      : (const char*)(hbuf + (size_t)(0 * MT + m) * HB_U64_PER);
#pragma unroll
  for (int k = 0; k < 16; ++k)
    gll16c(gb + ((size_t)(k * 256 + tid)) * 16, (void*)(hlds + (k * 256 + w * 64)));
  asm volatile("s_waitcnt vmcnt(0)" ::: "memory");
  __syncthreads();

  f32x4 aL[2][2];
  aL[0][0] = z4; aL[0][1] = z4; aL[1][0] = z4; aL[1][1] = z4;
#pragma unroll
  for (int c_ = 0; c_ < 8; ++c_) {
    const int kc_ = w * 8 + c_;
    uint4 A0 = hlds[(kc_ * 2 + 0) * 64 + l];
    uint4 A1 = hlds[(kc_ * 2 + 1) * 64 + l];
    uint4 O0 = wo[(size_t)(kc_ * 2 + 0) * 64 + l];
    uint4 O1 = wo[(size_t)(kc_ * 2 + 1) * 64 + l];
    half8 a0 = __builtin_bit_cast(half8, A0);
    half8 a1 = __builtin_bit_cast(half8, A1);
    half8 o0 = __builtin_bit_cast(half8, O0);
    half8 o1 = __builtin_bit_cast(half8, O1);
    aL[0][0] = MFMA16(a0, o0, aL[0][0]);
    aL[0][1] = MFMA16(a0, o1, aL[0][1]);
    aL[1][0] = MFMA16(a1, o0, aL[1][0]);
    aL[1][1] = MFMA16(a1, o1, aL[1][1]);
  }
  f32x4 sL;
#pragma unroll
  for (int o = 0; o < 4; ++o) {
    if (o == w) sL = aL[usub][uni];
    else {
      const int slot = (w > o) ? (w - 1) : w;
      redv[(o * 3 + slot) * 64 + l] = aL[o >> 1][o & 1];
    }
  }
  __syncthreads();
#pragma unroll
  for (int slot = 0; slot < 3; ++slot)
    sL += redv[(w * 3 + slot) * 64 + l];
  const int col = uni * 16 + l15;
  if (col < NL) {
#pragma unroll
    for (int rg = 0; rg < 4; ++rg) {
      const int row = usub * 16 + l4 * 4 + rg;
      const size_t b_ = (size_t)m * 32 + row;
      out[(b_ * NT + s) * NL + col] = sL[rg] + bout[col];
    }
  }
}

extern "C" void kernel_launch(void* const* d_in, const int* in_sizes, int n_in,
                              void* d_out, int out_size, void* d_ws, size_t ws_size,
                              hipStream_t stream) {
  (void)in_sizes; (void)n_in; (void)out_size;
  const float* seg   = (const float*)d_in[0];
  const int*   labels= (const int*)d_in[1];
  const float* emb   = (const float*)d_in[2];
  const float* Wih   = (const float*)d_in[3];
  const float* Whh   = (const float*)d_in[4];
  const float* bih   = (const float*)d_in[5];
  const float* bhh   = (const float*)d_in[6];
  const float* Wout  = (const float*)d_in[7];
  const float* bout  = (const float*)d_in[8];
  float* out = (float*)d_out;
  char* ws = (char*)d_ws;
  if (ws_size < WS_TOTAL) return;

  zero_ws<<<129, 256, 0, stream>>>((uint4*)(ws + WS_CNT));
  pack_w<<<3280, 256, 0, stream>>>(Wih, Whh, Wout,
                                   (u16*)(ws + WS_WPACK), (u16*)(ws + WS_WOPACK));
  pack_x<<<4096, 256, 0, stream>>>(seg, labels, emb, (u16*)(ws + WS_XPACK));
  gru_persist<<<NBLK, THREADS, 0, stream>>>(
      (u16*)(ws + WS_XPACK), (const u16*)(ws + WS_WPACK), bih, bhh,
      (u64*)(ws + WS_HBUF), (u32*)(ws + WS_CNT));
  logits_pass<<<MT * NT, 256, 0, stream>>>(
      (const u16*)(ws + WS_XPACK), (const u64*)(ws + WS_HBUF),
      (const u16*)(ws + WS_WOPACK), bout, out);
}